// Round 1
// baseline (6401.132 us; speedup 1.0000x reference)
//
#include <hip/hip_runtime.h>
#include <math.h>

#define NN   50000
#define NE   400000
#define NE2  (2*NE + NN)      // 850000 edges after symmetrize + self loops
#define DIM  256
#define NH   8
#define DPH  32
#define NM   (NN*DIM)         // 12,800,000 floats per activation buffer

// ---------------------------------------------------------------- SGEMM fp32
// C[M,Nc] = A[M,K] @ W[K,Nc] + bias ; tiles 64x64x32, 256 thr, 4x4/thread
__global__ __launch_bounds__(256) void sgemm_bias(
    const float* __restrict__ A, const float* __restrict__ W,
    const float* __restrict__ bias, float* __restrict__ C,
    int M, int K, int Nc)
{
    __shared__ float As[64][33];
    __shared__ float Ws[32][65];
    const int tid = threadIdx.x;
    const int tx = tid & 15, ty = tid >> 4;
    const int row0 = blockIdx.x * 64;
    const int col0 = blockIdx.y * 64;
    float acc[4][4] = {};
    for (int k0 = 0; k0 < K; k0 += 32) {
        #pragma unroll
        for (int i = 0; i < 8; ++i) {
            int lin = tid + i * 256;
            int r = lin >> 5, kk = lin & 31;
            int gr = row0 + r;
            As[r][kk] = (gr < M) ? A[(size_t)gr * K + k0 + kk] : 0.f;
        }
        #pragma unroll
        for (int i = 0; i < 8; ++i) {
            int lin = tid + i * 256;
            int kk = lin >> 6, c = lin & 63;
            Ws[kk][c] = W[(size_t)(k0 + kk) * Nc + col0 + c];
        }
        __syncthreads();
        #pragma unroll
        for (int kk = 0; kk < 32; ++kk) {
            float a[4], b[4];
            #pragma unroll
            for (int i = 0; i < 4; ++i) a[i] = As[ty*4+i][kk];
            #pragma unroll
            for (int j = 0; j < 4; ++j) b[j] = Ws[kk][tx*4+j];
            #pragma unroll
            for (int i = 0; i < 4; ++i)
                #pragma unroll
                for (int j = 0; j < 4; ++j)
                    acc[i][j] = fmaf(a[i], b[j], acc[i][j]);
        }
        __syncthreads();
    }
    #pragma unroll
    for (int i = 0; i < 4; ++i) {
        int gr = row0 + ty*4 + i;
        if (gr < M) {
            #pragma unroll
            for (int j = 0; j < 4; ++j) {
                int gc = col0 + tx*4 + j;
                C[(size_t)gr * Nc + gc] = acc[i][j] + bias[gc];
            }
        }
    }
}

// ------------------------------------------------- per-node attention scores
// s_l[n,h] = sum_d H[n,h*32+d]*a_l[h,d] ; same for s_r. One block per node.
__global__ __launch_bounds__(256) void gat_scores(
    const float* __restrict__ H, const float* __restrict__ a_l,
    const float* __restrict__ a_r, float* __restrict__ s_l,
    float* __restrict__ s_r)
{
    const int n = blockIdx.x;
    const int t = threadIdx.x;
    float v = H[n * DIM + t];
    float pl = v * a_l[t];
    float pr = v * a_r[t];
    #pragma unroll
    for (int o = 16; o > 0; o >>= 1) {
        pl += __shfl_down(pl, o, 32);
        pr += __shfl_down(pr, o, 32);
    }
    if ((t & 31) == 0) {
        int h = t >> 5;
        s_l[n * NH + h] = pl;
        s_r[n * NH + h] = pr;
    }
}

// edge decode: e2 in [0,NE): (ei0,ei1); [NE,2NE): reversed; [2NE,NE2): self
__device__ __forceinline__ void edge_sd(const int* __restrict__ ei, int e2,
                                        int& s, int& d)
{
    if (e2 < NE)          { s = ei[e2];      d = ei[e2 + NE]; }
    else if (e2 < 2 * NE) { s = ei[e2];      d = ei[e2 - NE]; }   // ei[NE+(e2-NE)]
    else                  { s = e2 - 2 * NE; d = s; }
}

// ------------------------------------------- denom[dst,h] += exp(logit) pass
__global__ __launch_bounds__(256) void gat_denom(
    const int* __restrict__ ei, const float* __restrict__ s_l,
    const float* __restrict__ s_r, float* __restrict__ denom)
{
    long gid = (long)blockIdx.x * 256 + threadIdx.x;
    if (gid >= (long)NE2 * NH) return;
    int e2 = (int)(gid >> 3);
    int h  = (int)(gid & 7);
    int s, d;
    edge_sd(ei, e2, s, d);
    float e = expf(s_l[s * NH + h] + s_r[d * NH + h]);
    atomicAdd(&denom[d * NH + h], e);
}

// ----------------------------------- message aggregation: one wave per edge
__global__ __launch_bounds__(256) void gat_aggregate(
    const int* __restrict__ ei, const float* __restrict__ H,
    const float* __restrict__ s_l, const float* __restrict__ s_r,
    const float* __restrict__ denom, float* __restrict__ out)
{
    long gid = (long)blockIdx.x * 256 + threadIdx.x;
    int wave = (int)(gid >> 6);
    int lane = (int)(gid & 63);
    if (wave >= NE2) return;
    int s, d;
    edge_sd(ei, wave, s, d);
    int h = lane >> 3;                       // 4 consecutive elems share a head
    float e = expf(s_l[s * NH + h] + s_r[d * NH + h]);
    float alpha = e / (denom[d * NH + h] + 1e-12f);
    const float4 hv = *reinterpret_cast<const float4*>(&H[s * DIM + lane * 4]);
    float* ob = &out[d * DIM + lane * 4];
    atomicAdd(ob + 0, hv.x * alpha);
    atomicAdd(ob + 1, hv.y * alpha);
    atomicAdd(ob + 2, hv.z * alpha);
    atomicAdd(ob + 3, hv.w * alpha);
}

// ------------------------------------------------------- BatchNorm (train)
__global__ __launch_bounds__(256) void bn_partial(
    const float* __restrict__ H, float* __restrict__ sums)
{
    const int c = threadIdx.x;
    const int r0 = blockIdx.x * 256;
    const int r1 = min(r0 + 256, NN);
    float s = 0.f, q = 0.f;
    for (int r = r0; r < r1; ++r) {
        float v = H[(size_t)r * DIM + c];
        s += v;
        q = fmaf(v, v, q);
    }
    atomicAdd(&sums[c], s);
    atomicAdd(&sums[DIM + c], q);
}

__global__ void bn_finalize(const float* __restrict__ sums,
    const float* __restrict__ g, const float* __restrict__ be,
    float* __restrict__ ss)
{
    const int c = threadIdx.x;  // 256 threads
    float mean = sums[c] * (1.f / NN);
    float var  = sums[DIM + c] * (1.f / NN) - mean * mean;
    float sc   = g[c] * rsqrtf(var + 1e-5f);
    ss[c]       = sc;
    ss[DIM + c] = be[c] - mean * sc;
}

__global__ __launch_bounds__(256) void bn_apply_relu(
    const float* __restrict__ in, const float* __restrict__ ss,
    float* __restrict__ out)
{
    int idx = blockIdx.x * 256 + threadIdx.x;   // float4 index
    if (idx >= NM / 4) return;
    int c4 = (idx & 63) * 4;                     // (idx*4) % 256
    float4 v = reinterpret_cast<const float4*>(in)[idx];
    float4 r;
    r.x = fmaxf(0.f, fmaf(v.x, ss[c4 + 0], ss[DIM + c4 + 0]));
    r.y = fmaxf(0.f, fmaf(v.y, ss[c4 + 1], ss[DIM + c4 + 1]));
    r.z = fmaxf(0.f, fmaf(v.z, ss[c4 + 2], ss[DIM + c4 + 2]));
    r.w = fmaxf(0.f, fmaf(v.w, ss[c4 + 3], ss[DIM + c4 + 3]));
    reinterpret_cast<float4*>(out)[idx] = r;
}

// ---------------------------------------------------------------------------
extern "C" void kernel_launch(void* const* d_in, const int* in_sizes, int n_in,
                              void* d_out, int out_size, void* d_ws, size_t ws_size,
                              hipStream_t stream)
{
    const float* x   = (const float*)d_in[0];
    const int*   ei  = (const int*)  d_in[1];
    const float* W1  = (const float*)d_in[2];
    const float* b1  = (const float*)d_in[3];
    const float* al1 = (const float*)d_in[4];
    const float* ar1 = (const float*)d_in[5];
    const float* g1  = (const float*)d_in[6];
    const float* be1 = (const float*)d_in[7];
    const float* W2  = (const float*)d_in[8];
    const float* b2  = (const float*)d_in[9];
    const float* al2 = (const float*)d_in[10];
    const float* ar2 = (const float*)d_in[11];
    const float* g2  = (const float*)d_in[12];
    const float* be2 = (const float*)d_in[13];
    const float* Wh  = (const float*)d_in[14];
    const float* bh  = (const float*)d_in[15];
    float* out = (float*)d_out;

    float* ws    = (float*)d_ws;
    float* bufA  = ws;                 // NM floats
    float* bufB  = ws + (size_t)NM;    // NM floats
    float* s_l   = ws + (size_t)2 * NM;
    float* s_r   = s_l + NN * NH;
    float* denom = s_r + NN * NH;
    float* bnsum = denom + NN * NH;
    float* ss    = bnsum + 2 * DIM;

    const dim3 gemmGrid(782, 4);       // 782*64 = 50048 rows, 4*64 = 256 cols
    const dim3 headGrid(782, 2);       // 128 cols
    const int denomBlocks = (int)(((long)NE2 * NH + 255) / 256);
    const int aggBlocks   = (int)(((long)NE2 * 64 + 255) / 256);
    const int bnpBlocks   = (NN + 255) / 256;      // 196
    const int applyBlocks = NM / 4 / 256;          // 12500

    // ---------------- layer 1
    sgemm_bias<<<gemmGrid, 256, 0, stream>>>(x, W1, b1, bufA, NN, DIM, DIM);
    gat_scores<<<NN, 256, 0, stream>>>(bufA, al1, ar1, s_l, s_r);
    hipMemsetAsync(denom, 0, (size_t)NN * NH * sizeof(float), stream);
    gat_denom<<<denomBlocks, 256, 0, stream>>>(ei, s_l, s_r, denom);
    hipMemsetAsync(bufB, 0, (size_t)NM * sizeof(float), stream);
    gat_aggregate<<<aggBlocks, 256, 0, stream>>>(ei, bufA, s_l, s_r, denom, bufB);
    hipMemsetAsync(bnsum, 0, 2 * DIM * sizeof(float), stream);
    bn_partial<<<bnpBlocks, 256, 0, stream>>>(bufB, bnsum);
    bn_finalize<<<1, 256, 0, stream>>>(bnsum, g1, be1, ss);
    bn_apply_relu<<<applyBlocks, 256, 0, stream>>>(bufB, ss, bufA);

    // ---------------- layer 2
    sgemm_bias<<<gemmGrid, 256, 0, stream>>>(bufA, W2, b2, bufB, NN, DIM, DIM);
    gat_scores<<<NN, 256, 0, stream>>>(bufB, al2, ar2, s_l, s_r);
    hipMemsetAsync(denom, 0, (size_t)NN * NH * sizeof(float), stream);
    gat_denom<<<denomBlocks, 256, 0, stream>>>(ei, s_l, s_r, denom);
    hipMemsetAsync(bufA, 0, (size_t)NM * sizeof(float), stream);
    gat_aggregate<<<aggBlocks, 256, 0, stream>>>(ei, bufB, s_l, s_r, denom, bufA);
    hipMemsetAsync(bnsum, 0, 2 * DIM * sizeof(float), stream);
    bn_partial<<<bnpBlocks, 256, 0, stream>>>(bufA, bnsum);
    bn_finalize<<<1, 256, 0, stream>>>(bnsum, g2, be2, ss);
    bn_apply_relu<<<applyBlocks, 256, 0, stream>>>(bufA, ss, bufB);

    // ---------------- classification head
    sgemm_bias<<<headGrid, 256, 0, stream>>>(bufB, Wh, bh, out, NN, DIM, 128);
}

// Round 2
// 1022.041 us; speedup vs baseline: 6.2631x; 6.2631x over previous
//
#include <hip/hip_runtime.h>
#include <math.h>

#define NN   50000
#define NE   400000
#define NE2  (2*NE + NN)      // 850000 edges after symmetrize + self loops
#define DIM  256
#define NH   8
#define DPH  32
#define NM   (NN*DIM)         // 12,800,000 floats per activation buffer
#define NBLK 196              // ceil(NN/256) blocks for scan

// ---------------------------------------------------------------- SGEMM fp32
// C[M,Nc] = A[M,K] @ W[K,Nc] + bias ; tiles 64x64x32, 256 thr, 4x4/thread
__global__ __launch_bounds__(256) void sgemm_bias(
    const float* __restrict__ A, const float* __restrict__ W,
    const float* __restrict__ bias, float* __restrict__ C,
    int M, int K, int Nc)
{
    __shared__ float As[64][33];
    __shared__ float Ws[32][65];
    const int tid = threadIdx.x;
    const int tx = tid & 15, ty = tid >> 4;
    const int row0 = blockIdx.x * 64;
    const int col0 = blockIdx.y * 64;
    float acc[4][4] = {};
    for (int k0 = 0; k0 < K; k0 += 32) {
        #pragma unroll
        for (int i = 0; i < 8; ++i) {
            int lin = tid + i * 256;
            int r = lin >> 5, kk = lin & 31;
            int gr = row0 + r;
            As[r][kk] = (gr < M) ? A[(size_t)gr * K + k0 + kk] : 0.f;
        }
        #pragma unroll
        for (int i = 0; i < 8; ++i) {
            int lin = tid + i * 256;
            int kk = lin >> 6, c = lin & 63;
            Ws[kk][c] = W[(size_t)(k0 + kk) * Nc + col0 + c];
        }
        __syncthreads();
        #pragma unroll
        for (int kk = 0; kk < 32; ++kk) {
            float a[4], b[4];
            #pragma unroll
            for (int i = 0; i < 4; ++i) a[i] = As[ty*4+i][kk];
            #pragma unroll
            for (int j = 0; j < 4; ++j) b[j] = Ws[kk][tx*4+j];
            #pragma unroll
            for (int i = 0; i < 4; ++i)
                #pragma unroll
                for (int j = 0; j < 4; ++j)
                    acc[i][j] = fmaf(a[i], b[j], acc[i][j]);
        }
        __syncthreads();
    }
    #pragma unroll
    for (int i = 0; i < 4; ++i) {
        int gr = row0 + ty*4 + i;
        if (gr < M) {
            #pragma unroll
            for (int j = 0; j < 4; ++j) {
                int gc = col0 + tx*4 + j;
                C[(size_t)gr * Nc + gc] = acc[i][j] + bias[gc];
            }
        }
    }
}

// ------------------------------------------------- per-node attention scores
__global__ __launch_bounds__(256) void gat_scores(
    const float* __restrict__ H, const float* __restrict__ a_l,
    const float* __restrict__ a_r, float* __restrict__ s_l,
    float* __restrict__ s_r)
{
    const int n = blockIdx.x;
    const int t = threadIdx.x;
    float v = H[n * DIM + t];
    float pl = v * a_l[t];
    float pr = v * a_r[t];
    #pragma unroll
    for (int o = 16; o > 0; o >>= 1) {
        pl += __shfl_down(pl, o, 32);
        pr += __shfl_down(pr, o, 32);
    }
    if ((t & 31) == 0) {
        int h = t >> 5;
        s_l[n * NH + h] = pl;
        s_r[n * NH + h] = pr;
    }
}

// edge decode: e2 in [0,NE): (ei0,ei1); [NE,2NE): reversed; [2NE,NE2): self
__device__ __forceinline__ void edge_sd(const int* __restrict__ ei, int e2,
                                        int& s, int& d)
{
    if (e2 < NE)          { s = ei[e2];      d = ei[e2 + NE]; }
    else if (e2 < 2 * NE) { s = ei[e2];      d = ei[e2 - NE]; }
    else                  { s = e2 - 2 * NE; d = s; }
}

// --------------------------------------------------------------- CSR build
__global__ __launch_bounds__(256) void deg_count(const int* __restrict__ ei,
                                                 int* __restrict__ deg)
{
    int e2 = blockIdx.x * 256 + threadIdx.x;
    if (e2 >= NE2) return;
    int s, d;
    edge_sd(ei, e2, s, d);
    atomicAdd(&deg[d], 1);
}

__global__ __launch_bounds__(256) void scan_block_sums(
    const int* __restrict__ deg, int* __restrict__ bsum)
{
    __shared__ int tmp[256];
    const int t = threadIdx.x;
    int i = blockIdx.x * 256 + t;
    tmp[t] = (i < NN) ? deg[i] : 0;
    __syncthreads();
    #pragma unroll
    for (int o = 128; o > 0; o >>= 1) {
        if (t < o) tmp[t] += tmp[t + o];
        __syncthreads();
    }
    if (t == 0) bsum[blockIdx.x] = tmp[0];
}

__global__ void scan_bsum(int* __restrict__ bsum)   // 1 block, 256 threads
{
    __shared__ int tmp[256];
    const int t = threadIdx.x;
    int v = (t < NBLK) ? bsum[t] : 0;
    tmp[t] = v;
    __syncthreads();
    #pragma unroll
    for (int o = 1; o < 256; o <<= 1) {
        int x = (t >= o) ? tmp[t - o] : 0;
        __syncthreads();
        tmp[t] += x;
        __syncthreads();
    }
    bsum[t] = tmp[t] - v;   // exclusive prefix of block sums
}

__global__ __launch_bounds__(256) void scan_write(
    const int* __restrict__ deg, const int* __restrict__ bsum,
    int* __restrict__ rowoff)
{
    __shared__ int tmp[256];
    const int t = threadIdx.x;
    int i = blockIdx.x * 256 + t;
    int v = (i < NN) ? deg[i] : 0;
    tmp[t] = v;
    __syncthreads();
    #pragma unroll
    for (int o = 1; o < 256; o <<= 1) {
        int x = (t >= o) ? tmp[t - o] : 0;
        __syncthreads();
        tmp[t] += x;
        __syncthreads();
    }
    if (i <= NN) rowoff[i] = bsum[blockIdx.x] + tmp[t] - v;
}

__global__ __launch_bounds__(256) void csr_fill(
    const int* __restrict__ ei, const int* __restrict__ rowoff,
    int* __restrict__ cursor, int* __restrict__ csr)
{
    int e2 = blockIdx.x * 256 + threadIdx.x;
    if (e2 >= NE2) return;
    int s, d;
    edge_sd(ei, e2, s, d);
    int pos = atomicAdd(&cursor[d], 1);
    csr[rowoff[d] + pos] = s;
}

// ------------------------- fused softmax-denominator + aggregation, no atomics
// out[n] = (sum_e exp(logit_e) * H[src_e]) / (sum_e exp(logit_e) + eps)
__global__ __launch_bounds__(256) void gat_aggregate_csr(
    const int* __restrict__ csr, const int* __restrict__ rowoff,
    const float* __restrict__ H, const float* __restrict__ s_l,
    const float* __restrict__ s_r, float* __restrict__ out)
{
    const int wid  = (blockIdx.x * 256 + threadIdx.x) >> 6;   // node id
    const int lane = threadIdx.x & 63;
    if (wid >= NN) return;
    const int h = lane >> 3;
    const float srd = s_r[wid * NH + h];
    const int i0 = rowoff[wid], i1 = rowoff[wid + 1];
    float ax = 0.f, ay = 0.f, az = 0.f, aw = 0.f, den = 0.f;
    for (int i = i0; i < i1; ++i) {
        int s = csr[i];
        float e = expf(s_l[s * NH + h] + srd);
        const float4 hv = *reinterpret_cast<const float4*>(&H[s * DIM + lane * 4]);
        ax = fmaf(hv.x, e, ax);
        ay = fmaf(hv.y, e, ay);
        az = fmaf(hv.z, e, az);
        aw = fmaf(hv.w, e, aw);
        den += e;
    }
    float inv = 1.f / (den + 1e-12f);
    float4 r = { ax * inv, ay * inv, az * inv, aw * inv };
    *reinterpret_cast<float4*>(&out[wid * DIM + lane * 4]) = r;
}

// ------------------------------------------------------- BatchNorm (train)
__global__ __launch_bounds__(256) void bn_partial(
    const float* __restrict__ H, float* __restrict__ sums)
{
    const int c = threadIdx.x;
    const int r0 = blockIdx.x * 256;
    const int r1 = min(r0 + 256, NN);
    float s = 0.f, q = 0.f;
    for (int r = r0; r < r1; ++r) {
        float v = H[(size_t)r * DIM + c];
        s += v;
        q = fmaf(v, v, q);
    }
    atomicAdd(&sums[c], s);
    atomicAdd(&sums[DIM + c], q);
}

__global__ void bn_finalize(const float* __restrict__ sums,
    const float* __restrict__ g, const float* __restrict__ be,
    float* __restrict__ ss)
{
    const int c = threadIdx.x;  // 256 threads
    float mean = sums[c] * (1.f / NN);
    float var  = sums[DIM + c] * (1.f / NN) - mean * mean;
    float sc   = g[c] * rsqrtf(var + 1e-5f);
    ss[c]       = sc;
    ss[DIM + c] = be[c] - mean * sc;
}

__global__ __launch_bounds__(256) void bn_apply_relu(
    const float* __restrict__ in, const float* __restrict__ ss,
    float* __restrict__ out)
{
    int idx = blockIdx.x * 256 + threadIdx.x;   // float4 index
    if (idx >= NM / 4) return;
    int c4 = (idx & 63) * 4;
    float4 v = reinterpret_cast<const float4*>(in)[idx];
    float4 r;
    r.x = fmaxf(0.f, fmaf(v.x, ss[c4 + 0], ss[DIM + c4 + 0]));
    r.y = fmaxf(0.f, fmaf(v.y, ss[c4 + 1], ss[DIM + c4 + 1]));
    r.z = fmaxf(0.f, fmaf(v.z, ss[c4 + 2], ss[DIM + c4 + 2]));
    r.w = fmaxf(0.f, fmaf(v.w, ss[c4 + 3], ss[DIM + c4 + 3]));
    reinterpret_cast<float4*>(out)[idx] = r;
}

// ---------------------------------------------------------------------------
extern "C" void kernel_launch(void* const* d_in, const int* in_sizes, int n_in,
                              void* d_out, int out_size, void* d_ws, size_t ws_size,
                              hipStream_t stream)
{
    const float* x   = (const float*)d_in[0];
    const int*   ei  = (const int*)  d_in[1];
    const float* W1  = (const float*)d_in[2];
    const float* b1  = (const float*)d_in[3];
    const float* al1 = (const float*)d_in[4];
    const float* ar1 = (const float*)d_in[5];
    const float* g1  = (const float*)d_in[6];
    const float* be1 = (const float*)d_in[7];
    const float* W2  = (const float*)d_in[8];
    const float* b2  = (const float*)d_in[9];
    const float* al2 = (const float*)d_in[10];
    const float* ar2 = (const float*)d_in[11];
    const float* g2  = (const float*)d_in[12];
    const float* be2 = (const float*)d_in[13];
    const float* Wh  = (const float*)d_in[14];
    const float* bh  = (const float*)d_in[15];
    float* out = (float*)d_out;

    float* ws    = (float*)d_ws;
    float* bufA  = ws;                 // NM floats
    float* bufB  = ws + (size_t)NM;    // NM floats
    float* s_l   = ws + (size_t)2 * NM;     // NN*NH
    float* s_r   = s_l + NN * NH;           // NN*NH
    float* bnsum = s_r + NN * NH;           // 2*DIM
    float* ss    = bnsum + 2 * DIM;         // 2*DIM
    int*   deg    = (int*)(ss + 2 * DIM);   // NN
    int*   rowoff = deg + NN;               // NN+1
    int*   cursor = rowoff + NN + 1;        // NN
    int*   bsum   = cursor + NN;            // 256
    int*   csr    = bsum + 256;             // NE2

    const dim3 gemmGrid(782, 4);       // 782*64 = 50048 rows, 4*64 = 256 cols
    const dim3 headGrid(782, 2);       // 128 cols
    const int edgeBlocks = (NE2 + 255) / 256;       // 3321
    const int aggBlocks  = (NN * 64 + 255) / 256;   // 12500
    const int bnpBlocks  = (NN + 255) / 256;        // 196
    const int applyBlocks = NM / 4 / 256;           // 12500

    // ---------------- CSR build (same graph both layers)
    hipMemsetAsync(deg, 0, NN * sizeof(int), stream);
    hipMemsetAsync(cursor, 0, NN * sizeof(int), stream);
    deg_count<<<edgeBlocks, 256, 0, stream>>>(ei, deg);
    scan_block_sums<<<NBLK, 256, 0, stream>>>(deg, bsum);
    scan_bsum<<<1, 256, 0, stream>>>(bsum);
    scan_write<<<NBLK, 256, 0, stream>>>(deg, bsum, rowoff);
    csr_fill<<<edgeBlocks, 256, 0, stream>>>(ei, rowoff, cursor, csr);

    // ---------------- layer 1
    sgemm_bias<<<gemmGrid, 256, 0, stream>>>(x, W1, b1, bufA, NN, DIM, DIM);
    gat_scores<<<NN, 256, 0, stream>>>(bufA, al1, ar1, s_l, s_r);
    gat_aggregate_csr<<<aggBlocks, 256, 0, stream>>>(csr, rowoff, bufA, s_l, s_r, bufB);
    hipMemsetAsync(bnsum, 0, 2 * DIM * sizeof(float), stream);
    bn_partial<<<bnpBlocks, 256, 0, stream>>>(bufB, bnsum);
    bn_finalize<<<1, 256, 0, stream>>>(bnsum, g1, be1, ss);
    bn_apply_relu<<<applyBlocks, 256, 0, stream>>>(bufB, ss, bufA);

    // ---------------- layer 2
    sgemm_bias<<<gemmGrid, 256, 0, stream>>>(bufA, W2, b2, bufB, NN, DIM, DIM);
    gat_scores<<<NN, 256, 0, stream>>>(bufB, al2, ar2, s_l, s_r);
    gat_aggregate_csr<<<aggBlocks, 256, 0, stream>>>(csr, rowoff, bufB, s_l, s_r, bufA);
    hipMemsetAsync(bnsum, 0, 2 * DIM * sizeof(float), stream);
    bn_partial<<<bnpBlocks, 256, 0, stream>>>(bufA, bnsum);
    bn_finalize<<<1, 256, 0, stream>>>(bnsum, g2, be2, ss);
    bn_apply_relu<<<applyBlocks, 256, 0, stream>>>(bufA, ss, bufB);

    // ---------------- classification head
    sgemm_bias<<<headGrid, 256, 0, stream>>>(bufB, Wh, bh, out, NN, DIM, 128);
}

// Round 3
// 674.206 us; speedup vs baseline: 9.4943x; 1.5159x over previous
//
#include <hip/hip_runtime.h>
#include <hip/hip_bf16.h>
#include <math.h>

#define NN   50000
#define NE   400000
#define NE2  (2*NE + NN)      // 850000 edges after symmetrize + self loops
#define DIM  256
#define NH   8
#define NM   (NN*DIM)         // 12,800,000 floats per activation buffer
#define NBLK 196              // ceil(NN/256) blocks for scan
#define MPAD 50048            // 391*128, padded row count for bf16 activations

typedef __attribute__((ext_vector_type(8))) short bf16x8;
typedef __attribute__((ext_vector_type(4))) float f32x4;

#define GLOAD16(g, l) __builtin_amdgcn_global_load_lds( \
    (const __attribute__((address_space(1))) void*)(g), \
    (__attribute__((address_space(3))) void*)(l), 16, 0, 0)

// ------------------------------------------------------------- bf16 MFMA GEMM
// C[M,Nc] = A[M,256] @ Bt[Nc,256]^T + bias.  A,Bt bf16 row-major; C fp32.
// grid (ceil(M/128), Nc/128); 256 thr = 4 waves in 2x2, each wave 64x64 out.
__global__ __launch_bounds__(256) void gemm_bf16(
    const __hip_bfloat16* __restrict__ A, const __hip_bfloat16* __restrict__ Bt,
    const float* __restrict__ bias, float* __restrict__ C,
    int M, int Nc)
{
    __shared__ short ldsA[4][128][8];   // [k-chunk][row][8 bf16] = 8 KiB
    __shared__ short ldsB[4][128][8];
    const int tid  = threadIdx.x;
    const int wave = tid >> 6, lane = tid & 63;
    const int wr = wave >> 1, wc = wave & 1;
    const int l15 = lane & 15, lk = lane >> 4;
    const int row0 = blockIdx.x * 128;
    const int col0 = blockIdx.y * 128;

    f32x4 acc[4][4] = {};
    for (int k0 = 0; k0 < 256; k0 += 32) {
        #pragma unroll
        for (int c = 0; c < 2; ++c) {
            int idx = c * 256 + tid;        // 0..511
            int ch = idx >> 7, r = idx & 127;
            GLOAD16(A  + (size_t)(row0 + r) * 256 + k0 + ch * 8, &ldsA[ch][r][0]);
            GLOAD16(Bt + (size_t)(col0 + r) * 256 + k0 + ch * 8, &ldsB[ch][r][0]);
        }
        __syncthreads();
        bf16x8 af[4], bf[4];
        #pragma unroll
        for (int m = 0; m < 4; ++m)
            af[m] = *reinterpret_cast<const bf16x8*>(&ldsA[lk][wr*64 + m*16 + l15][0]);
        #pragma unroll
        for (int n = 0; n < 4; ++n)
            bf[n] = *reinterpret_cast<const bf16x8*>(&ldsB[lk][wc*64 + n*16 + l15][0]);
        #pragma unroll
        for (int m = 0; m < 4; ++m)
            #pragma unroll
            for (int n = 0; n < 4; ++n)
                acc[m][n] = __builtin_amdgcn_mfma_f32_16x16x32_bf16(af[m], bf[n], acc[m][n], 0, 0, 0);
        __syncthreads();
    }
    #pragma unroll
    for (int m = 0; m < 4; ++m) {
        #pragma unroll
        for (int n = 0; n < 4; ++n) {
            int col = col0 + wc*64 + n*16 + l15;
            float bv = bias[col];
            #pragma unroll
            for (int r = 0; r < 4; ++r) {
                int row = row0 + wr*64 + m*16 + lk*4 + r;
                if (row < M) C[(size_t)row * Nc + col] = acc[m][n][r] + bv;
            }
        }
    }
}

// --------------------------------------------------------------- cast kernels
__global__ __launch_bounds__(256) void cast_x_bf16(
    const float* __restrict__ x, __hip_bfloat16* __restrict__ xb)
{
    int idx = blockIdx.x * 256 + threadIdx.x;     // float4 index
    if (idx >= NM / 4) return;
    float4 v = reinterpret_cast<const float4*>(x)[idx];
    __hip_bfloat16 o4[4] = {__float2bfloat16(v.x), __float2bfloat16(v.y),
                            __float2bfloat16(v.z), __float2bfloat16(v.w)};
    *reinterpret_cast<uint2*>(&xb[(size_t)idx * 4]) = *reinterpret_cast<const uint2*>(o4);
}

// W [K,Nc] fp32 -> Wt [Nc,K] bf16
__global__ __launch_bounds__(256) void cast_wt(
    const float* __restrict__ W, __hip_bfloat16* __restrict__ Wt, int K, int Nc)
{
    int i = blockIdx.x * 256 + threadIdx.x;
    if (i >= K * Nc) return;
    int k = i / Nc, n = i - k * Nc;
    Wt[n * K + k] = __float2bfloat16(W[i]);
}

// ------------------------------------------------- per-node attention scores
__global__ __launch_bounds__(256) void gat_scores(
    const float* __restrict__ H, const float* __restrict__ a_l,
    const float* __restrict__ a_r, float* __restrict__ s_l,
    float* __restrict__ s_r)
{
    const int n = blockIdx.x;
    const int t = threadIdx.x;
    float v = H[n * DIM + t];
    float pl = v * a_l[t];
    float pr = v * a_r[t];
    #pragma unroll
    for (int o = 16; o > 0; o >>= 1) {
        pl += __shfl_down(pl, o, 32);
        pr += __shfl_down(pr, o, 32);
    }
    if ((t & 31) == 0) {
        int h = t >> 5;
        s_l[n * NH + h] = pl;
        s_r[n * NH + h] = pr;
    }
}

// edge decode: e2 in [0,NE): (ei0,ei1); [NE,2NE): reversed; [2NE,NE2): self
__device__ __forceinline__ void edge_sd(const int* __restrict__ ei, int e2,
                                        int& s, int& d)
{
    if (e2 < NE)          { s = ei[e2];      d = ei[e2 + NE]; }
    else if (e2 < 2 * NE) { s = ei[e2];      d = ei[e2 - NE]; }
    else                  { s = e2 - 2 * NE; d = s; }
}

// --------------------------------------------------------------- CSR build
__global__ __launch_bounds__(256) void deg_count(const int* __restrict__ ei,
                                                 int* __restrict__ deg)
{
    int e2 = blockIdx.x * 256 + threadIdx.x;
    if (e2 >= NE2) return;
    int s, d;
    edge_sd(ei, e2, s, d);
    atomicAdd(&deg[d], 1);
}

__global__ __launch_bounds__(256) void scan_block_sums(
    const int* __restrict__ deg, int* __restrict__ bsum)
{
    __shared__ int tmp[256];
    const int t = threadIdx.x;
    int i = blockIdx.x * 256 + t;
    tmp[t] = (i < NN) ? deg[i] : 0;
    __syncthreads();
    #pragma unroll
    for (int o = 128; o > 0; o >>= 1) {
        if (t < o) tmp[t] += tmp[t + o];
        __syncthreads();
    }
    if (t == 0) bsum[blockIdx.x] = tmp[0];
}

__global__ void scan_bsum(int* __restrict__ bsum)   // 1 block, 256 threads
{
    __shared__ int tmp[256];
    const int t = threadIdx.x;
    int v = (t < NBLK) ? bsum[t] : 0;
    tmp[t] = v;
    __syncthreads();
    #pragma unroll
    for (int o = 1; o < 256; o <<= 1) {
        int x = (t >= o) ? tmp[t - o] : 0;
        __syncthreads();
        tmp[t] += x;
        __syncthreads();
    }
    bsum[t] = tmp[t] - v;   // exclusive prefix of block sums
}

__global__ __launch_bounds__(256) void scan_write(
    const int* __restrict__ deg, const int* __restrict__ bsum,
    int* __restrict__ rowoff)
{
    __shared__ int tmp[256];
    const int t = threadIdx.x;
    int i = blockIdx.x * 256 + t;
    int v = (i < NN) ? deg[i] : 0;
    tmp[t] = v;
    __syncthreads();
    #pragma unroll
    for (int o = 1; o < 256; o <<= 1) {
        int x = (t >= o) ? tmp[t - o] : 0;
        __syncthreads();
        tmp[t] += x;
        __syncthreads();
    }
    if (i <= NN) rowoff[i] = bsum[blockIdx.x] + tmp[t] - v;
}

__global__ __launch_bounds__(256) void csr_fill(
    const int* __restrict__ ei, const int* __restrict__ rowoff,
    int* __restrict__ cursor, int* __restrict__ csr)
{
    int e2 = blockIdx.x * 256 + threadIdx.x;
    if (e2 >= NE2) return;
    int s, d;
    edge_sd(ei, e2, s, d);
    int pos = atomicAdd(&cursor[d], 1);
    csr[rowoff[d] + pos] = s;
}

// ------------------------- fused softmax-denominator + aggregation, no atomics
__global__ __launch_bounds__(256) void gat_aggregate_csr(
    const int* __restrict__ csr, const int* __restrict__ rowoff,
    const float* __restrict__ H, const float* __restrict__ s_l,
    const float* __restrict__ s_r, float* __restrict__ out)
{
    const int wid  = (blockIdx.x * 256 + threadIdx.x) >> 6;   // node id
    const int lane = threadIdx.x & 63;
    if (wid >= NN) return;
    const int h = lane >> 3;
    const float srd = s_r[wid * NH + h];
    const int i0 = rowoff[wid], i1 = rowoff[wid + 1];
    float ax = 0.f, ay = 0.f, az = 0.f, aw = 0.f, den = 0.f;
    for (int i = i0; i < i1; ++i) {
        int s = csr[i];
        float e = expf(s_l[s * NH + h] + srd);
        const float4 hv = *reinterpret_cast<const float4*>(&H[s * DIM + lane * 4]);
        ax = fmaf(hv.x, e, ax);
        ay = fmaf(hv.y, e, ay);
        az = fmaf(hv.z, e, az);
        aw = fmaf(hv.w, e, aw);
        den += e;
    }
    float inv = 1.f / (den + 1e-12f);
    float4 r = { ax * inv, ay * inv, az * inv, aw * inv };
    *reinterpret_cast<float4*>(&out[wid * DIM + lane * 4]) = r;
}

// ------------------------------------------------------- BatchNorm (train)
__global__ __launch_bounds__(256) void bn_partial(
    const float* __restrict__ H, float* __restrict__ sums)
{
    const int c = threadIdx.x;
    const int r0 = blockIdx.x * 256;
    const int r1 = min(r0 + 256, NN);
    float s = 0.f, q = 0.f;
    for (int r = r0; r < r1; ++r) {
        float v = H[(size_t)r * DIM + c];
        s += v;
        q = fmaf(v, v, q);
    }
    atomicAdd(&sums[c], s);
    atomicAdd(&sums[DIM + c], q);
}

__global__ void bn_finalize(const float* __restrict__ sums,
    const float* __restrict__ g, const float* __restrict__ be,
    float* __restrict__ ss)
{
    const int c = threadIdx.x;  // 256 threads
    float mean = sums[c] * (1.f / NN);
    float var  = sums[DIM + c] * (1.f / NN) - mean * mean;
    float sc   = g[c] * rsqrtf(var + 1e-5f);
    ss[c]       = sc;
    ss[DIM + c] = be[c] - mean * sc;
}

// BN + ReLU, emitting bf16 (next consumer is always a bf16 GEMM)
__global__ __launch_bounds__(256) void bn_apply_relu_bf16(
    const float* __restrict__ in, const float* __restrict__ ss,
    __hip_bfloat16* __restrict__ out)
{
    int idx = blockIdx.x * 256 + threadIdx.x;   // float4 index
    if (idx >= NM / 4) return;
    int c4 = (idx & 63) * 4;
    float4 v = reinterpret_cast<const float4*>(in)[idx];
    float4 r;
    r.x = fmaxf(0.f, fmaf(v.x, ss[c4 + 0], ss[DIM + c4 + 0]));
    r.y = fmaxf(0.f, fmaf(v.y, ss[c4 + 1], ss[DIM + c4 + 1]));
    r.z = fmaxf(0.f, fmaf(v.z, ss[c4 + 2], ss[DIM + c4 + 2]));
    r.w = fmaxf(0.f, fmaf(v.w, ss[c4 + 3], ss[DIM + c4 + 3]));
    __hip_bfloat16 o4[4] = {__float2bfloat16(r.x), __float2bfloat16(r.y),
                            __float2bfloat16(r.z), __float2bfloat16(r.w)};
    *reinterpret_cast<uint2*>(&out[(size_t)idx * 4]) = *reinterpret_cast<const uint2*>(o4);
}

// ---------------------------------------------------------------------------
extern "C" void kernel_launch(void* const* d_in, const int* in_sizes, int n_in,
                              void* d_out, int out_size, void* d_ws, size_t ws_size,
                              hipStream_t stream)
{
    const float* x   = (const float*)d_in[0];
    const int*   ei  = (const int*)  d_in[1];
    const float* W1  = (const float*)d_in[2];
    const float* b1  = (const float*)d_in[3];
    const float* al1 = (const float*)d_in[4];
    const float* ar1 = (const float*)d_in[5];
    const float* g1  = (const float*)d_in[6];
    const float* be1 = (const float*)d_in[7];
    const float* W2  = (const float*)d_in[8];
    const float* b2  = (const float*)d_in[9];
    const float* al2 = (const float*)d_in[10];
    const float* ar2 = (const float*)d_in[11];
    const float* g2  = (const float*)d_in[12];
    const float* be2 = (const float*)d_in[13];
    const float* Wh  = (const float*)d_in[14];
    const float* bh  = (const float*)d_in[15];
    float* out = (float*)d_out;

    float* ws    = (float*)d_ws;
    float* bufA  = ws;                       // NM
    float* bufB  = ws + (size_t)NM;          // NM
    float* s_l   = ws + (size_t)2 * NM;      // NN*NH
    float* s_r   = s_l + NN * NH;            // NN*NH
    float* bnsum = s_r + NN * NH;            // 2*DIM
    float* ss    = bnsum + 2 * DIM;          // 2*DIM
    int*   deg    = (int*)(ss + 2 * DIM);    // NN
    int*   rowoff = deg + NN;                // NN+1
    int*   cursor = rowoff + NN + 1;         // NN
    int*   bsum   = cursor + NN;             // 256
    int*   csr    = bsum + 256;              // NE2
    __hip_bfloat16* xb =
        (__hip_bfloat16*)((((uintptr_t)(csr + NE2)) + 63) & ~(uintptr_t)63);  // MPAD*256
    __hip_bfloat16* Wt1 = xb + (size_t)MPAD * 256;   // 256*256
    __hip_bfloat16* Wt2 = Wt1 + 256 * 256;           // 256*256
    __hip_bfloat16* Wth = Wt2 + 256 * 256;           // 128*256

    const dim3 gemmGrid(MPAD / 128, 2);     // (391, 2)
    const dim3 headGrid(MPAD / 128, 1);
    const int edgeBlocks  = (NE2 + 255) / 256;       // 3321
    const int aggBlocks   = (NN * 64 + 255) / 256;   // 12500
    const int bnpBlocks   = (NN + 255) / 256;        // 196
    const int applyBlocks = NM / 4 / 256;            // 12500

    // ---------------- weight / input casts
    cast_wt<<<(256 * 256 + 255) / 256, 256, 0, stream>>>(W1, Wt1, 256, 256);
    cast_wt<<<(256 * 256 + 255) / 256, 256, 0, stream>>>(W2, Wt2, 256, 256);
    cast_wt<<<(256 * 128 + 255) / 256, 256, 0, stream>>>(Wh, Wth, 256, 128);
    cast_x_bf16<<<applyBlocks, 256, 0, stream>>>(x, xb);

    // ---------------- CSR build (same graph both layers)
    hipMemsetAsync(deg, 0, NN * sizeof(int), stream);
    hipMemsetAsync(cursor, 0, NN * sizeof(int), stream);
    deg_count<<<edgeBlocks, 256, 0, stream>>>(ei, deg);
    scan_block_sums<<<NBLK, 256, 0, stream>>>(deg, bsum);
    scan_bsum<<<1, 256, 0, stream>>>(bsum);
    scan_write<<<NBLK, 256, 0, stream>>>(deg, bsum, rowoff);
    csr_fill<<<edgeBlocks, 256, 0, stream>>>(ei, rowoff, cursor, csr);

    // ---------------- layer 1
    gemm_bf16<<<gemmGrid, 256, 0, stream>>>(xb, Wt1, b1, bufA, NN, 256);
    gat_scores<<<NN, 256, 0, stream>>>(bufA, al1, ar1, s_l, s_r);
    gat_aggregate_csr<<<aggBlocks, 256, 0, stream>>>(csr, rowoff, bufA, s_l, s_r, bufB);
    hipMemsetAsync(bnsum, 0, 2 * DIM * sizeof(float), stream);
    bn_partial<<<bnpBlocks, 256, 0, stream>>>(bufB, bnsum);
    bn_finalize<<<1, 256, 0, stream>>>(bnsum, g1, be1, ss);
    bn_apply_relu_bf16<<<applyBlocks, 256, 0, stream>>>(bufB, ss, xb);

    // ---------------- layer 2
    gemm_bf16<<<gemmGrid, 256, 0, stream>>>(xb, Wt2, b2, bufA, NN, 256);
    gat_scores<<<NN, 256, 0, stream>>>(bufA, al2, ar2, s_l, s_r);
    gat_aggregate_csr<<<aggBlocks, 256, 0, stream>>>(csr, rowoff, bufA, s_l, s_r, bufB);
    hipMemsetAsync(bnsum, 0, 2 * DIM * sizeof(float), stream);
    bn_partial<<<bnpBlocks, 256, 0, stream>>>(bufB, bnsum);
    bn_finalize<<<1, 256, 0, stream>>>(bnsum, g2, be2, ss);
    bn_apply_relu_bf16<<<applyBlocks, 256, 0, stream>>>(bufB, ss, xb);

    // ---------------- classification head
    gemm_bf16<<<headGrid, 256, 0, stream>>>(xb, Wth, bh, out, NN, 128);
}

// Round 4
// 565.989 us; speedup vs baseline: 11.3096x; 1.1912x over previous
//
#include <hip/hip_runtime.h>
#include <hip/hip_bf16.h>
#include <math.h>

#define NN   50000
#define NE   400000
#define NE2  (2*NE + NN)      // 850000 edges after symmetrize + self loops
#define DIM  256
#define NH   8
#define NM   (NN*DIM)         // 12,800,000 elements per activation buffer
#define NBLK 196              // ceil(NN/256) blocks for scan
#define MPAD 50048            // 391*128, padded row count for bf16 activations

typedef __attribute__((ext_vector_type(8))) short bf16x8;
typedef __attribute__((ext_vector_type(4))) float f32x4;

#define GLOAD16(g, l) __builtin_amdgcn_global_load_lds( \
    (const __attribute__((address_space(1))) void*)(g), \
    (__attribute__((address_space(3))) void*)(l), 16, 0, 0)

__device__ __forceinline__ float b2f(unsigned short u) {
    unsigned int i = ((unsigned int)u) << 16;
    float f; __builtin_memcpy(&f, &i, 4); return f;
}
__device__ __forceinline__ unsigned short f2b(float f) {
    __hip_bfloat16 h = __float2bfloat16(f);
    unsigned short u; __builtin_memcpy(&u, &h, 2); return u;
}

// ------------------------------------------------------------- bf16 MFMA GEMM
// C[M,Nc] = A[M,256] @ Bt[Nc,256]^T + bias.  A,Bt bf16 row-major.
// BF16OUT: write bf16 (unguarded, buffer padded to MPAD rows); else fp32, row<M.
template<bool BF16OUT>
__global__ __launch_bounds__(256) void gemm_bf16(
    const unsigned short* __restrict__ A, const unsigned short* __restrict__ Bt,
    const float* __restrict__ bias, float* __restrict__ C,
    unsigned short* __restrict__ Cb, int M, int Nc)
{
    __shared__ short ldsA[4][128][8];   // [k-chunk][row][8 bf16] = 8 KiB
    __shared__ short ldsB[4][128][8];
    const int tid  = threadIdx.x;
    const int wave = tid >> 6, lane = tid & 63;
    const int wr = wave >> 1, wc = wave & 1;
    const int l15 = lane & 15, lk = lane >> 4;
    const int row0 = blockIdx.x * 128;
    const int col0 = blockIdx.y * 128;

    f32x4 acc[4][4] = {};
    for (int k0 = 0; k0 < 256; k0 += 32) {
        #pragma unroll
        for (int c = 0; c < 2; ++c) {
            int idx = c * 256 + tid;        // 0..511
            int ch = idx >> 7, r = idx & 127;
            GLOAD16(A  + (size_t)(row0 + r) * 256 + k0 + ch * 8, &ldsA[ch][r][0]);
            GLOAD16(Bt + (size_t)(col0 + r) * 256 + k0 + ch * 8, &ldsB[ch][r][0]);
        }
        __syncthreads();
        bf16x8 af[4], bf[4];
        #pragma unroll
        for (int m = 0; m < 4; ++m)
            af[m] = *reinterpret_cast<const bf16x8*>(&ldsA[lk][wr*64 + m*16 + l15][0]);
        #pragma unroll
        for (int n = 0; n < 4; ++n)
            bf[n] = *reinterpret_cast<const bf16x8*>(&ldsB[lk][wc*64 + n*16 + l15][0]);
        #pragma unroll
        for (int m = 0; m < 4; ++m)
            #pragma unroll
            for (int n = 0; n < 4; ++n)
                acc[m][n] = __builtin_amdgcn_mfma_f32_16x16x32_bf16(af[m], bf[n], acc[m][n], 0, 0, 0);
        __syncthreads();
    }
    #pragma unroll
    for (int m = 0; m < 4; ++m) {
        #pragma unroll
        for (int n = 0; n < 4; ++n) {
            int col = col0 + wc*64 + n*16 + l15;
            float bv = bias[col];
            #pragma unroll
            for (int r = 0; r < 4; ++r) {
                int row = row0 + wr*64 + m*16 + lk*4 + r;
                if (BF16OUT) {
                    Cb[(size_t)row * Nc + col] = f2b(acc[m][n][r] + bv);
                } else {
                    if (row < M) C[(size_t)row * Nc + col] = acc[m][n][r] + bv;
                }
            }
        }
    }
}

// --------------------------------------------------------------- cast kernels
__global__ __launch_bounds__(256) void cast_x_bf16(
    const float* __restrict__ x, unsigned short* __restrict__ xb)
{
    int idx = blockIdx.x * 256 + threadIdx.x;     // float4 index
    if (idx >= NM / 4) return;
    float4 v = reinterpret_cast<const float4*>(x)[idx];
    ushort4 o = { f2b(v.x), f2b(v.y), f2b(v.z), f2b(v.w) };
    *reinterpret_cast<ushort4*>(&xb[(size_t)idx * 4]) = o;
}

// W [K,Nc] fp32 -> Wt [Nc,K] bf16
__global__ __launch_bounds__(256) void cast_wt(
    const float* __restrict__ W, unsigned short* __restrict__ Wt, int K, int Nc)
{
    int i = blockIdx.x * 256 + threadIdx.x;
    if (i >= K * Nc) return;
    int k = i / Nc, n = i - k * Nc;
    Wt[n * K + k] = f2b(W[i]);
}

// ------------------------------------------------- per-node attention scores
// wave per node: lane covers channels lane*4..lane*4+3 (all in head lane>>3)
__global__ __launch_bounds__(256) void gat_scores_bf16(
    const unsigned short* __restrict__ Hb, const float* __restrict__ a_l,
    const float* __restrict__ a_r, float* __restrict__ s_l,
    float* __restrict__ s_r)
{
    const int wave = threadIdx.x >> 6;
    const int lane = threadIdx.x & 63;
    const int n = blockIdx.x * 4 + wave;
    if (n >= NN) return;
    const int c = lane * 4;
    const int h = lane >> 3;
    ushort4 hv = *reinterpret_cast<const ushort4*>(&Hb[(size_t)n * DIM + c]);
    float4 al4 = *reinterpret_cast<const float4*>(&a_l[c]);
    float4 ar4 = *reinterpret_cast<const float4*>(&a_r[c]);
    float x0 = b2f(hv.x), x1 = b2f(hv.y), x2 = b2f(hv.z), x3 = b2f(hv.w);
    float pl = x0*al4.x + x1*al4.y + x2*al4.z + x3*al4.w;
    float pr = x0*ar4.x + x1*ar4.y + x2*ar4.z + x3*ar4.w;
    #pragma unroll
    for (int o = 1; o < 8; o <<= 1) {
        pl += __shfl_xor(pl, o, 64);
        pr += __shfl_xor(pr, o, 64);
    }
    if ((lane & 7) == 0) {
        s_l[n * NH + h] = pl;
        s_r[n * NH + h] = pr;
    }
}

// edge decode: e2 in [0,NE): (ei0,ei1); [NE,2NE): reversed; [2NE,NE2): self
__device__ __forceinline__ void edge_sd(const int* __restrict__ ei, int e2,
                                        int& s, int& d)
{
    if (e2 < NE)          { s = ei[e2];      d = ei[e2 + NE]; }
    else if (e2 < 2 * NE) { s = ei[e2];      d = ei[e2 - NE]; }
    else                  { s = e2 - 2 * NE; d = s; }
}

// --------------------------------------------------------------- CSR build
__global__ __launch_bounds__(256) void deg_count(const int* __restrict__ ei,
                                                 int* __restrict__ deg)
{
    int e2 = blockIdx.x * 256 + threadIdx.x;
    if (e2 >= NE2) return;
    int s, d;
    edge_sd(ei, e2, s, d);
    atomicAdd(&deg[d], 1);
}

__global__ __launch_bounds__(256) void scan_block_sums(
    const int* __restrict__ deg, int* __restrict__ bsum)
{
    __shared__ int tmp[256];
    const int t = threadIdx.x;
    int i = blockIdx.x * 256 + t;
    tmp[t] = (i < NN) ? deg[i] : 0;
    __syncthreads();
    #pragma unroll
    for (int o = 128; o > 0; o >>= 1) {
        if (t < o) tmp[t] += tmp[t + o];
        __syncthreads();
    }
    if (t == 0) bsum[blockIdx.x] = tmp[0];
}

__global__ void scan_bsum(int* __restrict__ bsum)   // 1 block, 256 threads
{
    __shared__ int tmp[256];
    const int t = threadIdx.x;
    int v = (t < NBLK) ? bsum[t] : 0;
    tmp[t] = v;
    __syncthreads();
    #pragma unroll
    for (int o = 1; o < 256; o <<= 1) {
        int x = (t >= o) ? tmp[t - o] : 0;
        __syncthreads();
        tmp[t] += x;
        __syncthreads();
    }
    bsum[t] = tmp[t] - v;   // exclusive prefix of block sums
}

__global__ __launch_bounds__(256) void scan_write(
    const int* __restrict__ deg, const int* __restrict__ bsum,
    int* __restrict__ rowoff)
{
    __shared__ int tmp[256];
    const int t = threadIdx.x;
    int i = blockIdx.x * 256 + t;
    int v = (i < NN) ? deg[i] : 0;
    tmp[t] = v;
    __syncthreads();
    #pragma unroll
    for (int o = 1; o < 256; o <<= 1) {
        int x = (t >= o) ? tmp[t - o] : 0;
        __syncthreads();
        tmp[t] += x;
        __syncthreads();
    }
    if (i <= NN) rowoff[i] = bsum[blockIdx.x] + tmp[t] - v;
}

__global__ __launch_bounds__(256) void csr_fill(
    const int* __restrict__ ei, const int* __restrict__ rowoff,
    int* __restrict__ cursor, int* __restrict__ csr)
{
    int e2 = blockIdx.x * 256 + threadIdx.x;
    if (e2 >= NE2) return;
    int s, d;
    edge_sd(ei, e2, s, d);
    int pos = atomicAdd(&cursor[d], 1);
    csr[rowoff[d] + pos] = s;
}

// ------------------------- fused softmax-denominator + aggregation, no atomics
__global__ __launch_bounds__(256) void gat_aggregate_csr_bf16(
    const int* __restrict__ csr, const int* __restrict__ rowoff,
    const unsigned short* __restrict__ Hb, const float* __restrict__ s_l,
    const float* __restrict__ s_r, unsigned short* __restrict__ outb)
{
    const int wid  = (blockIdx.x * 256 + threadIdx.x) >> 6;   // node id
    const int lane = threadIdx.x & 63;
    if (wid >= NN) return;
    const int h = lane >> 3;
    const float srd = s_r[wid * NH + h];
    const int i0 = rowoff[wid], i1 = rowoff[wid + 1];
    float ax = 0.f, ay = 0.f, az = 0.f, aw = 0.f, den = 0.f;
    for (int i = i0; i < i1; ++i) {
        int s = csr[i];
        float e = expf(s_l[s * NH + h] + srd);
        ushort4 hv = *reinterpret_cast<const ushort4*>(&Hb[(size_t)s * DIM + lane * 4]);
        ax = fmaf(b2f(hv.x), e, ax);
        ay = fmaf(b2f(hv.y), e, ay);
        az = fmaf(b2f(hv.z), e, az);
        aw = fmaf(b2f(hv.w), e, aw);
        den += e;
    }
    float inv = 1.f / (den + 1e-12f);
    ushort4 r = { f2b(ax * inv), f2b(ay * inv), f2b(az * inv), f2b(aw * inv) };
    *reinterpret_cast<ushort4*>(&outb[(size_t)wid * DIM + lane * 4]) = r;
}

// ------------------------------------------------------- BatchNorm (train)
__global__ __launch_bounds__(256) void bn_partial_bf16(
    const unsigned short* __restrict__ H, float* __restrict__ sums)
{
    const int c = threadIdx.x;
    const int r0 = blockIdx.x * 256;
    const int r1 = min(r0 + 256, NN);
    float s = 0.f, q = 0.f;
    for (int r = r0; r < r1; ++r) {
        float v = b2f(H[(size_t)r * DIM + c]);
        s += v;
        q = fmaf(v, v, q);
    }
    atomicAdd(&sums[c], s);
    atomicAdd(&sums[DIM + c], q);
}

// BN finalize (per-block, from sums) + affine + ReLU + bf16 out
__global__ __launch_bounds__(256) void bn_apply_relu_bf16(
    const unsigned short* __restrict__ in, const float* __restrict__ sums,
    const float* __restrict__ g, const float* __restrict__ be,
    unsigned short* __restrict__ out)
{
    __shared__ float sc[DIM], sh[DIM];
    const int t = threadIdx.x;
    {
        float mean = sums[t] * (1.f / NN);
        float var  = sums[DIM + t] * (1.f / NN) - mean * mean;
        float s    = g[t] * rsqrtf(var + 1e-5f);
        sc[t] = s;
        sh[t] = be[t] - mean * s;
    }
    __syncthreads();
    int idx = blockIdx.x * 256 + t;     // ushort4 index
    if (idx >= NM / 4) return;
    int c4 = (idx & 63) * 4;
    ushort4 v = reinterpret_cast<const ushort4*>(in)[idx];
    ushort4 r = {
        f2b(fmaxf(0.f, fmaf(b2f(v.x), sc[c4 + 0], sh[c4 + 0]))),
        f2b(fmaxf(0.f, fmaf(b2f(v.y), sc[c4 + 1], sh[c4 + 1]))),
        f2b(fmaxf(0.f, fmaf(b2f(v.z), sc[c4 + 2], sh[c4 + 2]))),
        f2b(fmaxf(0.f, fmaf(b2f(v.w), sc[c4 + 3], sh[c4 + 3]))) };
    reinterpret_cast<ushort4*>(out)[idx] = r;
}

// ---------------------------------------------------------------------------
extern "C" void kernel_launch(void* const* d_in, const int* in_sizes, int n_in,
                              void* d_out, int out_size, void* d_ws, size_t ws_size,
                              hipStream_t stream)
{
    const float* x   = (const float*)d_in[0];
    const int*   ei  = (const int*)  d_in[1];
    const float* W1  = (const float*)d_in[2];
    const float* b1  = (const float*)d_in[3];
    const float* al1 = (const float*)d_in[4];
    const float* ar1 = (const float*)d_in[5];
    const float* g1  = (const float*)d_in[6];
    const float* be1 = (const float*)d_in[7];
    const float* W2  = (const float*)d_in[8];
    const float* b2  = (const float*)d_in[9];
    const float* al2 = (const float*)d_in[10];
    const float* ar2 = (const float*)d_in[11];
    const float* g2  = (const float*)d_in[12];
    const float* be2 = (const float*)d_in[13];
    const float* Wh  = (const float*)d_in[14];
    const float* bh  = (const float*)d_in[15];
    float* out = (float*)d_out;

    float* ws     = (float*)d_ws;
    float* s_l    = ws;                      // NN*NH
    float* s_r    = s_l + NN * NH;           // NN*NH
    float* bnsum1 = s_r + NN * NH;           // 2*DIM
    float* bnsum2 = bnsum1 + 2 * DIM;        // 2*DIM  (adjacent: one memset)
    int*   deg    = (int*)(bnsum2 + 2 * DIM);// NN
    int*   cursor = deg + NN;                // NN     (adjacent: one memset)
    int*   rowoff = cursor + NN;             // NN+1
    int*   bsum   = rowoff + NN + 1;         // 256
    int*   csr    = bsum + 256;              // NE2
    unsigned short* xb =
        (unsigned short*)((((uintptr_t)(csr + NE2)) + 63) & ~(uintptr_t)63);
    unsigned short* Hb  = xb  + (size_t)MPAD * 256;  // MPAD*256
    unsigned short* Ab  = Hb  + (size_t)MPAD * 256;  // NN*256
    unsigned short* Wt1 = Ab  + (size_t)NN * 256;    // 256*256
    unsigned short* Wt2 = Wt1 + 256 * 256;
    unsigned short* Wth = Wt2 + 256 * 256;           // 128*256

    const dim3 gemmGrid(MPAD / 128, 2);     // (391, 2)
    const dim3 headGrid(MPAD / 128, 1);
    const int edgeBlocks  = (NE2 + 255) / 256;       // 3321
    const int nodeBlocks  = (NN * 64 + 255) / 256;   // 12500 (wave per node)
    const int bnpBlocks   = (NN + 255) / 256;        // 196
    const int elemBlocks  = NM / 4 / 256;            // 12500

    // ---------------- weight / input casts
    cast_wt<<<(256 * 256 + 255) / 256, 256, 0, stream>>>(W1, Wt1, 256, 256);
    cast_wt<<<(256 * 256 + 255) / 256, 256, 0, stream>>>(W2, Wt2, 256, 256);
    cast_wt<<<(256 * 128 + 255) / 256, 256, 0, stream>>>(Wh, Wth, 256, 128);
    cast_x_bf16<<<elemBlocks, 256, 0, stream>>>(x, xb);

    // ---------------- zero scratch (deg+cursor adjacent; bnsum1+bnsum2 adjacent)
    hipMemsetAsync(deg, 0, 2 * NN * sizeof(int), stream);
    hipMemsetAsync(bnsum1, 0, 4 * DIM * sizeof(float), stream);

    // ---------------- CSR build (same graph both layers)
    deg_count<<<edgeBlocks, 256, 0, stream>>>(ei, deg);
    scan_block_sums<<<NBLK, 256, 0, stream>>>(deg, bsum);
    scan_bsum<<<1, 256, 0, stream>>>(bsum);
    scan_write<<<NBLK, 256, 0, stream>>>(deg, bsum, rowoff);
    csr_fill<<<edgeBlocks, 256, 0, stream>>>(ei, rowoff, cursor, csr);

    // ---------------- layer 1
    gemm_bf16<true><<<gemmGrid, 256, 0, stream>>>(xb, Wt1, b1, nullptr, Hb, MPAD, 256);
    gat_scores_bf16<<<nodeBlocks / 1, 256, 0, stream>>>(Hb, al1, ar1, s_l, s_r);
    gat_aggregate_csr_bf16<<<nodeBlocks, 256, 0, stream>>>(csr, rowoff, Hb, s_l, s_r, Ab);
    bn_partial_bf16<<<bnpBlocks, 256, 0, stream>>>(Ab, bnsum1);
    bn_apply_relu_bf16<<<elemBlocks, 256, 0, stream>>>(Ab, bnsum1, g1, be1, xb);

    // ---------------- layer 2
    gemm_bf16<true><<<gemmGrid, 256, 0, stream>>>(xb, Wt2, b2, nullptr, Hb, MPAD, 256);
    gat_scores_bf16<<<nodeBlocks / 1, 256, 0, stream>>>(Hb, al2, ar2, s_l, s_r);
    gat_aggregate_csr_bf16<<<nodeBlocks, 256, 0, stream>>>(csr, rowoff, Hb, s_l, s_r, Ab);
    bn_partial_bf16<<<bnpBlocks, 256, 0, stream>>>(Ab, bnsum2);
    bn_apply_relu_bf16<<<elemBlocks, 256, 0, stream>>>(Ab, bnsum2, g2, be2, xb);

    // ---------------- classification head
    gemm_bf16<false><<<headGrid, 256, 0, stream>>>(xb, Wth, bh, out, nullptr, NN, 128);
}

// Round 5
// 561.806 us; speedup vs baseline: 11.3938x; 1.0074x over previous
//
#include <hip/hip_runtime.h>
#include <hip/hip_bf16.h>
#include <math.h>

#define NN   50000
#define NE   400000
#define NE2  (2*NE + NN)      // 850000 edges after symmetrize + self loops
#define DIM  256
#define NH   8
#define NM   (NN*DIM)         // 12,800,000 elements per activation buffer
#define NBLK 196              // ceil(NN/256) blocks for scan
#define MPAD 50048            // 391*128, padded row count for bf16 activations

typedef __attribute__((ext_vector_type(8))) short bf16x8;
typedef __attribute__((ext_vector_type(4))) float f32x4;

#define GLOAD16(g, l) __builtin_amdgcn_global_load_lds( \
    (const __attribute__((address_space(1))) void*)(g), \
    (__attribute__((address_space(3))) void*)(l), 16, 0, 0)

__device__ __forceinline__ float b2f(unsigned short u) {
    unsigned int i = ((unsigned int)u) << 16;
    float f; __builtin_memcpy(&f, &i, 4); return f;
}
__device__ __forceinline__ unsigned short f2b(float f) {
    __hip_bfloat16 h = __float2bfloat16(f);
    unsigned short u; __builtin_memcpy(&u, &h, 2); return u;
}

// ------------------------------------------------------------- bf16 MFMA GEMM
// C[M,Nc] = A[M,256] @ Bt[Nc,256]^T + bias.  A,Bt bf16 row-major.
// BF16OUT: write bf16 (unguarded, buffer padded to MPAD rows); else fp32, row<M.
template<bool BF16OUT>
__global__ __launch_bounds__(256) void gemm_bf16(
    const unsigned short* __restrict__ A, const unsigned short* __restrict__ Bt,
    const float* __restrict__ bias, float* __restrict__ C,
    unsigned short* __restrict__ Cb, int M, int Nc)
{
    __shared__ short ldsA[4][128][8];   // [k-chunk][row][8 bf16] = 8 KiB
    __shared__ short ldsB[4][128][8];
    const int tid  = threadIdx.x;
    const int wave = tid >> 6, lane = tid & 63;
    const int wr = wave >> 1, wc = wave & 1;
    const int l15 = lane & 15, lk = lane >> 4;
    const int row0 = blockIdx.x * 128;
    const int col0 = blockIdx.y * 128;

    f32x4 acc[4][4] = {};
    for (int k0 = 0; k0 < 256; k0 += 32) {
        #pragma unroll
        for (int c = 0; c < 2; ++c) {
            int idx = c * 256 + tid;        // 0..511
            int ch = idx >> 7, r = idx & 127;
            GLOAD16(A  + (size_t)(row0 + r) * 256 + k0 + ch * 8, &ldsA[ch][r][0]);
            GLOAD16(Bt + (size_t)(col0 + r) * 256 + k0 + ch * 8, &ldsB[ch][r][0]);
        }
        __syncthreads();
        bf16x8 af[4], bf[4];
        #pragma unroll
        for (int m = 0; m < 4; ++m)
            af[m] = *reinterpret_cast<const bf16x8*>(&ldsA[lk][wr*64 + m*16 + l15][0]);
        #pragma unroll
        for (int n = 0; n < 4; ++n)
            bf[n] = *reinterpret_cast<const bf16x8*>(&ldsB[lk][wc*64 + n*16 + l15][0]);
        #pragma unroll
        for (int m = 0; m < 4; ++m)
            #pragma unroll
            for (int n = 0; n < 4; ++n)
                acc[m][n] = __builtin_amdgcn_mfma_f32_16x16x32_bf16(af[m], bf[n], acc[m][n], 0, 0, 0);
        __syncthreads();
    }
    #pragma unroll
    for (int m = 0; m < 4; ++m) {
        #pragma unroll
        for (int n = 0; n < 4; ++n) {
            int col = col0 + wc*64 + n*16 + l15;
            float bv = bias[col];
            #pragma unroll
            for (int r = 0; r < 4; ++r) {
                int row = row0 + wr*64 + m*16 + lk*4 + r;
                if (BF16OUT) {
                    Cb[(size_t)row * Nc + col] = f2b(acc[m][n][r] + bv);
                } else {
                    if (row < M) C[(size_t)row * Nc + col] = acc[m][n][r] + bv;
                }
            }
        }
    }
}

// --------------------------------------------------------------- cast kernels
__global__ __launch_bounds__(256) void cast_x_bf16(
    const float* __restrict__ x, unsigned short* __restrict__ xb)
{
    int idx = blockIdx.x * 256 + threadIdx.x;     // float4 index
    if (idx >= NM / 4) return;
    float4 v = reinterpret_cast<const float4*>(x)[idx];
    ushort4 o = { f2b(v.x), f2b(v.y), f2b(v.z), f2b(v.w) };
    *reinterpret_cast<ushort4*>(&xb[(size_t)idx * 4]) = o;
}

// W [K,Nc] fp32 -> Wt [Nc,K] bf16
__global__ __launch_bounds__(256) void cast_wt(
    const float* __restrict__ W, unsigned short* __restrict__ Wt, int K, int Nc)
{
    int i = blockIdx.x * 256 + threadIdx.x;
    if (i >= K * Nc) return;
    int k = i / Nc, n = i - k * Nc;
    Wt[n * K + k] = f2b(W[i]);
}

// ------------------------------------------------- per-node attention factors
// wave per node; writes el = exp(<H[n],a_l>), er = exp(<H[n],a_r>) per head
__global__ __launch_bounds__(256) void gat_scores_bf16(
    const unsigned short* __restrict__ Hb, const float* __restrict__ a_l,
    const float* __restrict__ a_r, float* __restrict__ el,
    float* __restrict__ er)
{
    const int wave = threadIdx.x >> 6;
    const int lane = threadIdx.x & 63;
    const int n = blockIdx.x * 4 + wave;
    if (n >= NN) return;
    const int c = lane * 4;
    const int h = lane >> 3;
    ushort4 hv = *reinterpret_cast<const ushort4*>(&Hb[(size_t)n * DIM + c]);
    float4 al4 = *reinterpret_cast<const float4*>(&a_l[c]);
    float4 ar4 = *reinterpret_cast<const float4*>(&a_r[c]);
    float x0 = b2f(hv.x), x1 = b2f(hv.y), x2 = b2f(hv.z), x3 = b2f(hv.w);
    float pl = x0*al4.x + x1*al4.y + x2*al4.z + x3*al4.w;
    float pr = x0*ar4.x + x1*ar4.y + x2*ar4.z + x3*ar4.w;
    #pragma unroll
    for (int o = 1; o < 8; o <<= 1) {
        pl += __shfl_xor(pl, o, 64);
        pr += __shfl_xor(pr, o, 64);
    }
    if ((lane & 7) == 0) {
        el[n * NH + h] = expf(pl);
        er[n * NH + h] = expf(pr);
    }
}

// edge decode: e2 in [0,NE): (ei0,ei1); [NE,2NE): reversed; [2NE,NE2): self
__device__ __forceinline__ void edge_sd(const int* __restrict__ ei, int e2,
                                        int& s, int& d)
{
    if (e2 < NE)          { s = ei[e2];      d = ei[e2 + NE]; }
    else if (e2 < 2 * NE) { s = ei[e2];      d = ei[e2 - NE]; }
    else                  { s = e2 - 2 * NE; d = s; }
}

// --------------------------------------------------------------- CSR build
__global__ __launch_bounds__(256) void deg_count(const int* __restrict__ ei,
                                                 int* __restrict__ deg)
{
    int e2 = blockIdx.x * 256 + threadIdx.x;
    if (e2 >= NE2) return;
    int s, d;
    edge_sd(ei, e2, s, d);
    atomicAdd(&deg[d], 1);
}

__global__ __launch_bounds__(256) void scan_block_sums(
    const int* __restrict__ deg, int* __restrict__ bsum)
{
    __shared__ int tmp[256];
    const int t = threadIdx.x;
    int i = blockIdx.x * 256 + t;
    tmp[t] = (i < NN) ? deg[i] : 0;
    __syncthreads();
    #pragma unroll
    for (int o = 128; o > 0; o >>= 1) {
        if (t < o) tmp[t] += tmp[t + o];
        __syncthreads();
    }
    if (t == 0) bsum[blockIdx.x] = tmp[0];
}

__global__ void scan_bsum(int* __restrict__ bsum)   // 1 block, 256 threads
{
    __shared__ int tmp[256];
    const int t = threadIdx.x;
    int v = (t < NBLK) ? bsum[t] : 0;
    tmp[t] = v;
    __syncthreads();
    #pragma unroll
    for (int o = 1; o < 256; o <<= 1) {
        int x = (t >= o) ? tmp[t - o] : 0;
        __syncthreads();
        tmp[t] += x;
        __syncthreads();
    }
    bsum[t] = tmp[t] - v;   // exclusive prefix of block sums
}

__global__ __launch_bounds__(256) void scan_write(
    const int* __restrict__ deg, const int* __restrict__ bsum,
    int* __restrict__ rowoff)
{
    __shared__ int tmp[256];
    const int t = threadIdx.x;
    int i = blockIdx.x * 256 + t;
    int v = (i < NN) ? deg[i] : 0;
    tmp[t] = v;
    __syncthreads();
    #pragma unroll
    for (int o = 1; o < 256; o <<= 1) {
        int x = (t >= o) ? tmp[t - o] : 0;
        __syncthreads();
        tmp[t] += x;
        __syncthreads();
    }
    if (i <= NN) rowoff[i] = bsum[blockIdx.x] + tmp[t] - v;
}

__global__ __launch_bounds__(256) void csr_fill(
    const int* __restrict__ ei, const int* __restrict__ rowoff,
    int* __restrict__ cursor, int* __restrict__ csr)
{
    int e2 = blockIdx.x * 256 + threadIdx.x;
    if (e2 >= NE2) return;
    int s, d;
    edge_sd(ei, e2, s, d);
    int pos = atomicAdd(&cursor[d], 1);
    csr[rowoff[d] + pos] = s;
}

// ------------------------- fused softmax + aggregation, no atomics, no expf
// out[d] = er[d]*sum(el[s]*H[s]) / (er[d]*sum(el[s]) + eps)
__global__ __launch_bounds__(256) void gat_aggregate_csr_bf16(
    const int* __restrict__ csr, const int* __restrict__ rowoff,
    const unsigned short* __restrict__ Hb, const float* __restrict__ el,
    const float* __restrict__ er, unsigned short* __restrict__ outb)
{
    const int wid  = (blockIdx.x * 256 + threadIdx.x) >> 6;   // node id
    const int lane = threadIdx.x & 63;
    if (wid >= NN) return;
    const int h = lane >> 3;
    const int i0 = rowoff[wid], i1 = rowoff[wid + 1];
    float ax = 0.f, ay = 0.f, az = 0.f, aw = 0.f, den = 0.f;
    for (int i = i0; i < i1; ++i) {
        int s = csr[i];
        float e = el[s * NH + h];
        ushort4 hv = *reinterpret_cast<const ushort4*>(&Hb[(size_t)s * DIM + lane * 4]);
        ax = fmaf(b2f(hv.x), e, ax);
        ay = fmaf(b2f(hv.y), e, ay);
        az = fmaf(b2f(hv.z), e, az);
        aw = fmaf(b2f(hv.w), e, aw);
        den += e;
    }
    float erv = er[wid * NH + h];
    float inv = erv / fmaf(den, erv, 1e-12f);
    ushort4 r = { f2b(ax * inv), f2b(ay * inv), f2b(az * inv), f2b(aw * inv) };
    *reinterpret_cast<ushort4*>(&outb[(size_t)wid * DIM + lane * 4]) = r;
}

// ------------------------------------------------------- BatchNorm (train)
__global__ __launch_bounds__(256) void bn_partial_bf16(
    const unsigned short* __restrict__ H, float* __restrict__ sums)
{
    const int c = threadIdx.x;
    const int r0 = blockIdx.x * 256;
    const int r1 = min(r0 + 256, NN);
    float s = 0.f, q = 0.f;
    for (int r = r0; r < r1; ++r) {
        float v = b2f(H[(size_t)r * DIM + c]);
        s += v;
        q = fmaf(v, v, q);
    }
    atomicAdd(&sums[c], s);
    atomicAdd(&sums[DIM + c], q);
}

// BN finalize (per-block, from sums) + affine + ReLU + bf16 out
__global__ __launch_bounds__(256) void bn_apply_relu_bf16(
    const unsigned short* __restrict__ in, const float* __restrict__ sums,
    const float* __restrict__ g, const float* __restrict__ be,
    unsigned short* __restrict__ out)
{
    __shared__ float sc[DIM], sh[DIM];
    const int t = threadIdx.x;
    {
        float mean = sums[t] * (1.f / NN);
        float var  = sums[DIM + t] * (1.f / NN) - mean * mean;
        float s    = g[t] * rsqrtf(var + 1e-5f);
        sc[t] = s;
        sh[t] = be[t] - mean * s;
    }
    __syncthreads();
    int idx = blockIdx.x * 256 + t;     // ushort4 index
    if (idx >= NM / 4) return;
    int c4 = (idx & 63) * 4;
    ushort4 v = reinterpret_cast<const ushort4*>(in)[idx];
    ushort4 r = {
        f2b(fmaxf(0.f, fmaf(b2f(v.x), sc[c4 + 0], sh[c4 + 0]))),
        f2b(fmaxf(0.f, fmaf(b2f(v.y), sc[c4 + 1], sh[c4 + 1]))),
        f2b(fmaxf(0.f, fmaf(b2f(v.z), sc[c4 + 2], sh[c4 + 2]))),
        f2b(fmaxf(0.f, fmaf(b2f(v.w), sc[c4 + 3], sh[c4 + 3]))) };
    reinterpret_cast<ushort4*>(out)[idx] = r;
}

// ---------------------------------------------------------------------------
extern "C" void kernel_launch(void* const* d_in, const int* in_sizes, int n_in,
                              void* d_out, int out_size, void* d_ws, size_t ws_size,
                              hipStream_t stream)
{
    const float* x   = (const float*)d_in[0];
    const int*   ei  = (const int*)  d_in[1];
    const float* W1  = (const float*)d_in[2];
    const float* b1  = (const float*)d_in[3];
    const float* al1 = (const float*)d_in[4];
    const float* ar1 = (const float*)d_in[5];
    const float* g1  = (const float*)d_in[6];
    const float* be1 = (const float*)d_in[7];
    const float* W2  = (const float*)d_in[8];
    const float* b2  = (const float*)d_in[9];
    const float* al2 = (const float*)d_in[10];
    const float* ar2 = (const float*)d_in[11];
    const float* g2  = (const float*)d_in[12];
    const float* be2 = (const float*)d_in[13];
    const float* Wh  = (const float*)d_in[14];
    const float* bh  = (const float*)d_in[15];
    float* out = (float*)d_out;

    float* ws     = (float*)d_ws;
    float* el     = ws;                      // NN*NH
    float* er     = el + NN * NH;            // NN*NH
    float* bnsum1 = er + NN * NH;            // 2*DIM
    float* bnsum2 = bnsum1 + 2 * DIM;        // 2*DIM  (adjacent: one memset)
    int*   deg    = (int*)(bnsum2 + 2 * DIM);// NN
    int*   cursor = deg + NN;                // NN     (adjacent: one memset)
    int*   rowoff = cursor + NN;             // NN+1
    int*   bsum   = rowoff + NN + 1;         // 256
    int*   csr    = bsum + 256;              // NE2
    unsigned short* xb =
        (unsigned short*)((((uintptr_t)(csr + NE2)) + 63) & ~(uintptr_t)63);
    unsigned short* Hb  = xb  + (size_t)MPAD * 256;  // MPAD*256
    unsigned short* Ab  = Hb  + (size_t)MPAD * 256;  // NN*256
    unsigned short* Wt1 = Ab  + (size_t)NN * 256;    // 256*256
    unsigned short* Wt2 = Wt1 + 256 * 256;
    unsigned short* Wth = Wt2 + 256 * 256;           // 128*256

    const dim3 gemmGrid(MPAD / 128, 2);     // (391, 2)
    const dim3 headGrid(MPAD / 128, 1);
    const int edgeBlocks  = (NE2 + 255) / 256;       // 3321
    const int nodeBlocks  = (NN * 64 + 255) / 256;   // 12500 (wave per node)
    const int bnpBlocks   = (NN + 255) / 256;        // 196
    const int elemBlocks  = NM / 4 / 256;            // 12500

    // ---------------- weight / input casts
    cast_wt<<<(256 * 256 + 255) / 256, 256, 0, stream>>>(W1, Wt1, 256, 256);
    cast_wt<<<(256 * 256 + 255) / 256, 256, 0, stream>>>(W2, Wt2, 256, 256);
    cast_wt<<<(256 * 128 + 255) / 256, 256, 0, stream>>>(Wh, Wth, 256, 128);
    cast_x_bf16<<<elemBlocks, 256, 0, stream>>>(x, xb);

    // ---------------- zero scratch (deg+cursor adjacent; bnsum1+bnsum2 adjacent)
    hipMemsetAsync(deg, 0, 2 * NN * sizeof(int), stream);
    hipMemsetAsync(bnsum1, 0, 4 * DIM * sizeof(float), stream);

    // ---------------- CSR build (same graph both layers)
    deg_count<<<edgeBlocks, 256, 0, stream>>>(ei, deg);
    scan_block_sums<<<NBLK, 256, 0, stream>>>(deg, bsum);
    scan_bsum<<<1, 256, 0, stream>>>(bsum);
    scan_write<<<NBLK, 256, 0, stream>>>(deg, bsum, rowoff);
    csr_fill<<<edgeBlocks, 256, 0, stream>>>(ei, rowoff, cursor, csr);

    // ---------------- layer 1
    gemm_bf16<true><<<gemmGrid, 256, 0, stream>>>(xb, Wt1, b1, nullptr, Hb, MPAD, 256);
    gat_scores_bf16<<<nodeBlocks, 256, 0, stream>>>(Hb, al1, ar1, el, er);
    gat_aggregate_csr_bf16<<<nodeBlocks, 256, 0, stream>>>(csr, rowoff, Hb, el, er, Ab);
    bn_partial_bf16<<<bnpBlocks, 256, 0, stream>>>(Ab, bnsum1);
    bn_apply_relu_bf16<<<elemBlocks, 256, 0, stream>>>(Ab, bnsum1, g1, be1, xb);

    // ---------------- layer 2
    gemm_bf16<true><<<gemmGrid, 256, 0, stream>>>(xb, Wt2, b2, nullptr, Hb, MPAD, 256);
    gat_scores_bf16<<<nodeBlocks, 256, 0, stream>>>(Hb, al2, ar2, el, er);
    gat_aggregate_csr_bf16<<<nodeBlocks, 256, 0, stream>>>(csr, rowoff, Hb, el, er, Ab);
    bn_partial_bf16<<<bnpBlocks, 256, 0, stream>>>(Ab, bnsum2);
    bn_apply_relu_bf16<<<elemBlocks, 256, 0, stream>>>(Ab, bnsum2, g2, be2, xb);

    // ---------------- classification head
    gemm_bf16<false><<<headGrid, 256, 0, stream>>>(xb, Wth, bh, out, nullptr, NN, 128);
}

// Round 6
// 512.500 us; speedup vs baseline: 12.4900x; 1.0962x over previous
//
#include <hip/hip_runtime.h>
#include <hip/hip_bf16.h>
#include <math.h>

#define NN   50000
#define NE   400000
#define NE2  (2*NE + NN)      // 850000 edges after symmetrize + self loops
#define DIM  256
#define NH   8
#define NM   (NN*DIM)         // 12,800,000 elements per activation buffer
#define NBLK 196              // ceil(NN/256) blocks for scan
#define MPAD 50048            // 391*128, padded row count for bf16 activations

typedef __attribute__((ext_vector_type(8))) short bf16x8;
typedef __attribute__((ext_vector_type(4))) float f32x4;

#define GLOAD16(g, l) __builtin_amdgcn_global_load_lds( \
    (const __attribute__((address_space(1))) void*)(g), \
    (__attribute__((address_space(3))) void*)(l), 16, 0, 0)

__device__ __forceinline__ float b2f(unsigned short u) {
    unsigned int i = ((unsigned int)u) << 16;
    float f; __builtin_memcpy(&f, &i, 4); return f;
}
__device__ __forceinline__ unsigned short f2b(float f) {
    __hip_bfloat16 h = __float2bfloat16(f);
    unsigned short u; __builtin_memcpy(&u, &h, 2); return u;
}

// ------------------------------------------------------------- bf16 MFMA GEMM
// C[M,Nc] = A[M,256] @ Bt[Nc,256]^T + bias.  A,Bt bf16 row-major.
// BF16OUT: write bf16 (unguarded, buffer padded to MPAD rows); else fp32, row<M.
template<bool BF16OUT>
__global__ __launch_bounds__(256) void gemm_bf16(
    const unsigned short* __restrict__ A, const unsigned short* __restrict__ Bt,
    const float* __restrict__ bias, float* __restrict__ C,
    unsigned short* __restrict__ Cb, int M, int Nc)
{
    __shared__ short ldsA[4][128][8];   // [k-chunk][row][8 bf16] = 8 KiB
    __shared__ short ldsB[4][128][8];
    const int tid  = threadIdx.x;
    const int wave = tid >> 6, lane = tid & 63;
    const int wr = wave >> 1, wc = wave & 1;
    const int l15 = lane & 15, lk = lane >> 4;
    const int row0 = blockIdx.x * 128;
    const int col0 = blockIdx.y * 128;

    f32x4 acc[4][4] = {};
    for (int k0 = 0; k0 < 256; k0 += 32) {
        #pragma unroll
        for (int c = 0; c < 2; ++c) {
            int idx = c * 256 + tid;        // 0..511
            int ch = idx >> 7, r = idx & 127;
            GLOAD16(A  + (size_t)(row0 + r) * 256 + k0 + ch * 8, &ldsA[ch][r][0]);
            GLOAD16(Bt + (size_t)(col0 + r) * 256 + k0 + ch * 8, &ldsB[ch][r][0]);
        }
        __syncthreads();
        bf16x8 af[4], bf[4];
        #pragma unroll
        for (int m = 0; m < 4; ++m)
            af[m] = *reinterpret_cast<const bf16x8*>(&ldsA[lk][wr*64 + m*16 + l15][0]);
        #pragma unroll
        for (int n = 0; n < 4; ++n)
            bf[n] = *reinterpret_cast<const bf16x8*>(&ldsB[lk][wc*64 + n*16 + l15][0]);
        #pragma unroll
        for (int m = 0; m < 4; ++m)
            #pragma unroll
            for (int n = 0; n < 4; ++n)
                acc[m][n] = __builtin_amdgcn_mfma_f32_16x16x32_bf16(af[m], bf[n], acc[m][n], 0, 0, 0);
        __syncthreads();
    }
    #pragma unroll
    for (int m = 0; m < 4; ++m) {
        #pragma unroll
        for (int n = 0; n < 4; ++n) {
            int col = col0 + wc*64 + n*16 + l15;
            float bv = bias[col];
            #pragma unroll
            for (int r = 0; r < 4; ++r) {
                int row = row0 + wr*64 + m*16 + lk*4 + r;
                if (BF16OUT) {
                    Cb[(size_t)row * Nc + col] = f2b(acc[m][n][r] + bv);
                } else {
                    if (row < M) C[(size_t)row * Nc + col] = acc[m][n][r] + bv;
                }
            }
        }
    }
}

// --------------------------------------------------------------- cast kernels
__global__ __launch_bounds__(256) void cast_x_bf16(
    const float* __restrict__ x, unsigned short* __restrict__ xb)
{
    int idx = blockIdx.x * 256 + threadIdx.x;     // float4 index
    if (idx >= NM / 4) return;
    float4 v = reinterpret_cast<const float4*>(x)[idx];
    ushort4 o = { f2b(v.x), f2b(v.y), f2b(v.z), f2b(v.w) };
    *reinterpret_cast<ushort4*>(&xb[(size_t)idx * 4]) = o;
}

// W [K,Nc] fp32 -> Wt [Nc,K] bf16
__global__ __launch_bounds__(256) void cast_wt(
    const float* __restrict__ W, unsigned short* __restrict__ Wt, int K, int Nc)
{
    int i = blockIdx.x * 256 + threadIdx.x;
    if (i >= K * Nc) return;
    int k = i / Nc, n = i - k * Nc;
    Wt[n * K + k] = f2b(W[i]);
}

// ------------------------------------------------- per-node attention factors
// wave per node; writes el = exp(<H[n],a_l>), er = exp(<H[n],a_r>) per head
__global__ __launch_bounds__(256) void gat_scores_bf16(
    const unsigned short* __restrict__ Hb, const float* __restrict__ a_l,
    const float* __restrict__ a_r, float* __restrict__ el,
    float* __restrict__ er)
{
    const int wave = threadIdx.x >> 6;
    const int lane = threadIdx.x & 63;
    const int n = blockIdx.x * 4 + wave;
    if (n >= NN) return;
    const int c = lane * 4;
    const int h = lane >> 3;
    ushort4 hv = *reinterpret_cast<const ushort4*>(&Hb[(size_t)n * DIM + c]);
    float4 al4 = *reinterpret_cast<const float4*>(&a_l[c]);
    float4 ar4 = *reinterpret_cast<const float4*>(&a_r[c]);
    float x0 = b2f(hv.x), x1 = b2f(hv.y), x2 = b2f(hv.z), x3 = b2f(hv.w);
    float pl = x0*al4.x + x1*al4.y + x2*al4.z + x3*al4.w;
    float pr = x0*ar4.x + x1*ar4.y + x2*ar4.z + x3*ar4.w;
    #pragma unroll
    for (int o = 1; o < 8; o <<= 1) {
        pl += __shfl_xor(pl, o, 64);
        pr += __shfl_xor(pr, o, 64);
    }
    if ((lane & 7) == 0) {
        el[n * NH + h] = expf(pl);
        er[n * NH + h] = expf(pr);
    }
}

// edge decode: e2 in [0,NE): (ei0,ei1); [NE,2NE): reversed; [2NE,NE2): self
__device__ __forceinline__ void edge_sd(const int* __restrict__ ei, int e2,
                                        int& s, int& d)
{
    if (e2 < NE)          { s = ei[e2];      d = ei[e2 + NE]; }
    else if (e2 < 2 * NE) { s = ei[e2];      d = ei[e2 - NE]; }
    else                  { s = e2 - 2 * NE; d = s; }
}

// --------------------------------------------------------------- CSR build
__global__ __launch_bounds__(256) void deg_count(const int* __restrict__ ei,
                                                 int* __restrict__ deg)
{
    int e2 = blockIdx.x * 256 + threadIdx.x;
    if (e2 >= NE2) return;
    int s, d;
    edge_sd(ei, e2, s, d);
    atomicAdd(&deg[d], 1);
}

__global__ __launch_bounds__(256) void scan_block_sums(
    const int* __restrict__ deg, int* __restrict__ bsum)
{
    __shared__ int tmp[256];
    const int t = threadIdx.x;
    int i = blockIdx.x * 256 + t;
    tmp[t] = (i < NN) ? deg[i] : 0;
    __syncthreads();
    #pragma unroll
    for (int o = 128; o > 0; o >>= 1) {
        if (t < o) tmp[t] += tmp[t + o];
        __syncthreads();
    }
    if (t == 0) bsum[blockIdx.x] = tmp[0];
}

__global__ void scan_bsum(int* __restrict__ bsum)   // 1 block, 256 threads
{
    __shared__ int tmp[256];
    const int t = threadIdx.x;
    int v = (t < NBLK) ? bsum[t] : 0;
    tmp[t] = v;
    __syncthreads();
    #pragma unroll
    for (int o = 1; o < 256; o <<= 1) {
        int x = (t >= o) ? tmp[t - o] : 0;
        __syncthreads();
        tmp[t] += x;
        __syncthreads();
    }
    bsum[t] = tmp[t] - v;   // exclusive prefix of block sums
}

__global__ __launch_bounds__(256) void scan_write(
    const int* __restrict__ deg, const int* __restrict__ bsum,
    int* __restrict__ rowoff)
{
    __shared__ int tmp[256];
    const int t = threadIdx.x;
    int i = blockIdx.x * 256 + t;
    int v = (i < NN) ? deg[i] : 0;
    tmp[t] = v;
    __syncthreads();
    #pragma unroll
    for (int o = 1; o < 256; o <<= 1) {
        int x = (t >= o) ? tmp[t - o] : 0;
        __syncthreads();
        tmp[t] += x;
        __syncthreads();
    }
    if (i <= NN) rowoff[i] = bsum[blockIdx.x] + tmp[t] - v;
}

__global__ __launch_bounds__(256) void csr_fill(
    const int* __restrict__ ei, const int* __restrict__ rowoff,
    int* __restrict__ cursor, int* __restrict__ csr)
{
    int e2 = blockIdx.x * 256 + threadIdx.x;
    if (e2 >= NE2) return;
    int s, d;
    edge_sd(ei, e2, s, d);
    int pos = atomicAdd(&cursor[d], 1);
    csr[rowoff[d] + pos] = s;
}

// ------------------------- fused softmax + aggregation, no atomics, no expf
// out[d] = er[d]*sum(el[s]*H[s]) / (er[d]*sum(el[s]) + eps)
// Edge loop unrolled x4: 4 independent row-gathers in flight per wave (MLP).
__global__ __launch_bounds__(256) void gat_aggregate_csr_bf16(
    const int* __restrict__ csr, const int* __restrict__ rowoff,
    const unsigned short* __restrict__ Hb, const float* __restrict__ el,
    const float* __restrict__ er, unsigned short* __restrict__ outb)
{
    const int wid  = (blockIdx.x * 256 + threadIdx.x) >> 6;   // node id
    const int lane = threadIdx.x & 63;
    if (wid >= NN) return;
    const int h = lane >> 3;
    const int i0 = rowoff[wid], i1 = rowoff[wid + 1];
    const int c4 = lane * 4;

    float ax0 = 0.f, ay0 = 0.f, az0 = 0.f, aw0 = 0.f, den0 = 0.f;
    float ax1 = 0.f, ay1 = 0.f, az1 = 0.f, aw1 = 0.f, den1 = 0.f;

    int i = i0;
    for (; i + 4 <= i1; i += 4) {
        int s0 = csr[i + 0], s1 = csr[i + 1], s2 = csr[i + 2], s3 = csr[i + 3];
        float e0 = el[s0 * NH + h], e1 = el[s1 * NH + h];
        float e2 = el[s2 * NH + h], e3 = el[s3 * NH + h];
        ushort4 h0 = *reinterpret_cast<const ushort4*>(&Hb[(size_t)s0 * DIM + c4]);
        ushort4 h1 = *reinterpret_cast<const ushort4*>(&Hb[(size_t)s1 * DIM + c4]);
        ushort4 h2 = *reinterpret_cast<const ushort4*>(&Hb[(size_t)s2 * DIM + c4]);
        ushort4 h3 = *reinterpret_cast<const ushort4*>(&Hb[(size_t)s3 * DIM + c4]);
        ax0 = fmaf(b2f(h0.x), e0, ax0); ay0 = fmaf(b2f(h0.y), e0, ay0);
        az0 = fmaf(b2f(h0.z), e0, az0); aw0 = fmaf(b2f(h0.w), e0, aw0);
        den0 += e0;
        ax1 = fmaf(b2f(h1.x), e1, ax1); ay1 = fmaf(b2f(h1.y), e1, ay1);
        az1 = fmaf(b2f(h1.z), e1, az1); aw1 = fmaf(b2f(h1.w), e1, aw1);
        den1 += e1;
        ax0 = fmaf(b2f(h2.x), e2, ax0); ay0 = fmaf(b2f(h2.y), e2, ay0);
        az0 = fmaf(b2f(h2.z), e2, az0); aw0 = fmaf(b2f(h2.w), e2, aw0);
        den0 += e2;
        ax1 = fmaf(b2f(h3.x), e3, ax1); ay1 = fmaf(b2f(h3.y), e3, ay1);
        az1 = fmaf(b2f(h3.z), e3, az1); aw1 = fmaf(b2f(h3.w), e3, aw1);
        den1 += e3;
    }
    for (; i < i1; ++i) {
        int s = csr[i];
        float e = el[s * NH + h];
        ushort4 hv = *reinterpret_cast<const ushort4*>(&Hb[(size_t)s * DIM + c4]);
        ax0 = fmaf(b2f(hv.x), e, ax0); ay0 = fmaf(b2f(hv.y), e, ay0);
        az0 = fmaf(b2f(hv.z), e, az0); aw0 = fmaf(b2f(hv.w), e, aw0);
        den0 += e;
    }
    float ax = ax0 + ax1, ay = ay0 + ay1, az = az0 + az1, aw = aw0 + aw1;
    float den = den0 + den1;
    float erv = er[wid * NH + h];
    float inv = erv / fmaf(den, erv, 1e-12f);
    ushort4 r = { f2b(ax * inv), f2b(ay * inv), f2b(az * inv), f2b(aw * inv) };
    *reinterpret_cast<ushort4*>(&outb[(size_t)wid * DIM + c4]) = r;
}

// ------------------------------------------------------- BatchNorm (train)
__global__ __launch_bounds__(256) void bn_partial_bf16(
    const unsigned short* __restrict__ H, float* __restrict__ sums)
{
    const int c = threadIdx.x;
    const int r0 = blockIdx.x * 256;
    const int r1 = min(r0 + 256, NN);
    float s = 0.f, q = 0.f;
    for (int r = r0; r < r1; ++r) {
        float v = b2f(H[(size_t)r * DIM + c]);
        s += v;
        q = fmaf(v, v, q);
    }
    atomicAdd(&sums[c], s);
    atomicAdd(&sums[DIM + c], q);
}

// BN finalize (per-block, from sums) + affine + ReLU + bf16 out
__global__ __launch_bounds__(256) void bn_apply_relu_bf16(
    const unsigned short* __restrict__ in, const float* __restrict__ sums,
    const float* __restrict__ g, const float* __restrict__ be,
    unsigned short* __restrict__ out)
{
    __shared__ float sc[DIM], sh[DIM];
    const int t = threadIdx.x;
    {
        float mean = sums[t] * (1.f / NN);
        float var  = sums[DIM + t] * (1.f / NN) - mean * mean;
        float s    = g[t] * rsqrtf(var + 1e-5f);
        sc[t] = s;
        sh[t] = be[t] - mean * s;
    }
    __syncthreads();
    int idx = blockIdx.x * 256 + t;     // ushort4 index
    if (idx >= NM / 4) return;
    int c4 = (idx & 63) * 4;
    ushort4 v = reinterpret_cast<const ushort4*>(in)[idx];
    ushort4 r = {
        f2b(fmaxf(0.f, fmaf(b2f(v.x), sc[c4 + 0], sh[c4 + 0]))),
        f2b(fmaxf(0.f, fmaf(b2f(v.y), sc[c4 + 1], sh[c4 + 1]))),
        f2b(fmaxf(0.f, fmaf(b2f(v.z), sc[c4 + 2], sh[c4 + 2]))),
        f2b(fmaxf(0.f, fmaf(b2f(v.w), sc[c4 + 3], sh[c4 + 3]))) };
    reinterpret_cast<ushort4*>(out)[idx] = r;
}

// ---------------------------------------------------------------------------
extern "C" void kernel_launch(void* const* d_in, const int* in_sizes, int n_in,
                              void* d_out, int out_size, void* d_ws, size_t ws_size,
                              hipStream_t stream)
{
    const float* x   = (const float*)d_in[0];
    const int*   ei  = (const int*)  d_in[1];
    const float* W1  = (const float*)d_in[2];
    const float* b1  = (const float*)d_in[3];
    const float* al1 = (const float*)d_in[4];
    const float* ar1 = (const float*)d_in[5];
    const float* g1  = (const float*)d_in[6];
    const float* be1 = (const float*)d_in[7];
    const float* W2  = (const float*)d_in[8];
    const float* b2  = (const float*)d_in[9];
    const float* al2 = (const float*)d_in[10];
    const float* ar2 = (const float*)d_in[11];
    const float* g2  = (const float*)d_in[12];
    const float* be2 = (const float*)d_in[13];
    const float* Wh  = (const float*)d_in[14];
    const float* bh  = (const float*)d_in[15];
    float* out = (float*)d_out;

    float* ws     = (float*)d_ws;
    float* el     = ws;                      // NN*NH
    float* er     = el + NN * NH;            // NN*NH
    float* bnsum1 = er + NN * NH;            // 2*DIM
    float* bnsum2 = bnsum1 + 2 * DIM;        // 2*DIM  (adjacent: one memset)
    int*   deg    = (int*)(bnsum2 + 2 * DIM);// NN
    int*   cursor = deg + NN;                // NN     (adjacent: one memset)
    int*   rowoff = cursor + NN;             // NN+1
    int*   bsum   = rowoff + NN + 1;         // 256
    int*   csr    = bsum + 256;              // NE2
    unsigned short* xb =
        (unsigned short*)((((uintptr_t)(csr + NE2)) + 63) & ~(uintptr_t)63);
    unsigned short* Hb  = xb  + (size_t)MPAD * 256;  // MPAD*256
    unsigned short* Ab  = Hb  + (size_t)MPAD * 256;  // NN*256
    unsigned short* Wt1 = Ab  + (size_t)NN * 256;    // 256*256
    unsigned short* Wt2 = Wt1 + 256 * 256;
    unsigned short* Wth = Wt2 + 256 * 256;           // 128*256

    const dim3 gemmGrid(MPAD / 128, 2);     // (391, 2)
    const dim3 headGrid(MPAD / 128, 1);
    const int edgeBlocks  = (NE2 + 255) / 256;       // 3321
    const int nodeBlocks  = (NN * 64 + 255) / 256;   // 12500 (wave per node)
    const int bnpBlocks   = (NN + 255) / 256;        // 196
    const int elemBlocks  = NM / 4 / 256;            // 12500

    // ---------------- weight / input casts
    cast_wt<<<(256 * 256 + 255) / 256, 256, 0, stream>>>(W1, Wt1, 256, 256);
    cast_wt<<<(256 * 256 + 255) / 256, 256, 0, stream>>>(W2, Wt2, 256, 256);
    cast_wt<<<(256 * 128 + 255) / 256, 256, 0, stream>>>(Wh, Wth, 256, 128);
    cast_x_bf16<<<elemBlocks, 256, 0, stream>>>(x, xb);

    // ---------------- zero scratch (deg+cursor adjacent; bnsum1+bnsum2 adjacent)
    hipMemsetAsync(deg, 0, 2 * NN * sizeof(int), stream);
    hipMemsetAsync(bnsum1, 0, 4 * DIM * sizeof(float), stream);

    // ---------------- CSR build (same graph both layers)
    deg_count<<<edgeBlocks, 256, 0, stream>>>(ei, deg);
    scan_block_sums<<<NBLK, 256, 0, stream>>>(deg, bsum);
    scan_bsum<<<1, 256, 0, stream>>>(bsum);
    scan_write<<<NBLK, 256, 0, stream>>>(deg, bsum, rowoff);
    csr_fill<<<edgeBlocks, 256, 0, stream>>>(ei, rowoff, cursor, csr);

    // ---------------- layer 1
    gemm_bf16<true><<<gemmGrid, 256, 0, stream>>>(xb, Wt1, b1, nullptr, Hb, MPAD, 256);
    gat_scores_bf16<<<nodeBlocks, 256, 0, stream>>>(Hb, al1, ar1, el, er);
    gat_aggregate_csr_bf16<<<nodeBlocks, 256, 0, stream>>>(csr, rowoff, Hb, el, er, Ab);
    bn_partial_bf16<<<bnpBlocks, 256, 0, stream>>>(Ab, bnsum1);
    bn_apply_relu_bf16<<<elemBlocks, 256, 0, stream>>>(Ab, bnsum1, g1, be1, xb);

    // ---------------- layer 2
    gemm_bf16<true><<<gemmGrid, 256, 0, stream>>>(xb, Wt2, b2, nullptr, Hb, MPAD, 256);
    gat_scores_bf16<<<nodeBlocks, 256, 0, stream>>>(Hb, al2, ar2, el, er);
    gat_aggregate_csr_bf16<<<nodeBlocks, 256, 0, stream>>>(csr, rowoff, Hb, el, er, Ab);
    bn_partial_bf16<<<bnpBlocks, 256, 0, stream>>>(Ab, bnsum2);
    bn_apply_relu_bf16<<<elemBlocks, 256, 0, stream>>>(Ab, bnsum2, g2, be2, xb);

    // ---------------- classification head
    gemm_bf16<false><<<headGrid, 256, 0, stream>>>(xb, Wth, bh, out, nullptr, NN, 128);
}

// Round 7
// 502.193 us; speedup vs baseline: 12.7464x; 1.0205x over previous
//
#include <hip/hip_runtime.h>
#include <hip/hip_bf16.h>
#include <math.h>

#define NN   50000
#define NE   400000
#define NE2  (2*NE + NN)      // 850000 edges after symmetrize + self loops
#define DIM  256
#define NH   8
#define NM   (NN*DIM)         // 12,800,000 elements per activation buffer
#define NBLK 196              // ceil(NN/256) blocks for scan
#define MPAD 50048            // 391*128, padded row count for bf16 activations

typedef __attribute__((ext_vector_type(8))) short bf16x8;
typedef __attribute__((ext_vector_type(4))) float f32x4;

#define GLOAD16(g, l) __builtin_amdgcn_global_load_lds( \
    (const __attribute__((address_space(1))) void*)(g), \
    (__attribute__((address_space(3))) void*)(l), 16, 0, 0)

__device__ __forceinline__ float b2f(unsigned short u) {
    unsigned int i = ((unsigned int)u) << 16;
    float f; __builtin_memcpy(&f, &i, 4); return f;
}
__device__ __forceinline__ unsigned short f2b(float f) {
    __hip_bfloat16 h = __float2bfloat16(f);
    unsigned short u; __builtin_memcpy(&u, &h, 2); return u;
}

// --------------------------------------------- wide bf16 MFMA GEMM (layers)
// Cb[MPAD,256] = A[MPAD,256] @ Bt[256,256]^T + bias, bf16 out, unguarded
// (buffer padded). 512 thr = 8 waves in 2(row)x4(col); tile 128x256; one
// col-block -> A read exactly once.
__global__ __launch_bounds__(512) void gemm_bf16_wide(
    const unsigned short* __restrict__ A, const unsigned short* __restrict__ Bt,
    const float* __restrict__ bias, unsigned short* __restrict__ Cb)
{
    __shared__ short ldsA[4][128][8];   // 8 KiB
    __shared__ short ldsB[4][256][8];   // 16 KiB
    const int tid  = threadIdx.x;
    const int wave = tid >> 6, lane = tid & 63;
    const int wr = wave >> 2, wc = wave & 3;
    const int l15 = lane & 15, lk = lane >> 4;
    const int row0 = blockIdx.x * 128;

    f32x4 acc[4][4] = {};
    for (int k0 = 0; k0 < 256; k0 += 32) {
        // A-tile: 128 rows x 32k = 8 KB -> one 16B gload per thread
        GLOAD16(A + (size_t)(row0 + (tid & 127)) * 256 + k0 + (tid >> 7) * 8,
                &ldsA[tid >> 7][tid & 127][0]);
        // B-tile: 256 rows x 32k = 16 KB -> two gloads per thread
        #pragma unroll
        for (int c = 0; c < 2; ++c) {
            int idx = c * 512 + tid;        // 0..1023
            int ch = idx >> 8, r = idx & 255;
            GLOAD16(Bt + (size_t)r * 256 + k0 + ch * 8, &ldsB[ch][r][0]);
        }
        __syncthreads();
        bf16x8 af[4], bf[4];
        #pragma unroll
        for (int m = 0; m < 4; ++m)
            af[m] = *reinterpret_cast<const bf16x8*>(&ldsA[lk][wr*64 + m*16 + l15][0]);
        #pragma unroll
        for (int n = 0; n < 4; ++n)
            bf[n] = *reinterpret_cast<const bf16x8*>(&ldsB[lk][wc*64 + n*16 + l15][0]);
        #pragma unroll
        for (int m = 0; m < 4; ++m)
            #pragma unroll
            for (int n = 0; n < 4; ++n)
                acc[m][n] = __builtin_amdgcn_mfma_f32_16x16x32_bf16(af[m], bf[n], acc[m][n], 0, 0, 0);
        __syncthreads();
    }
    #pragma unroll
    for (int m = 0; m < 4; ++m) {
        #pragma unroll
        for (int n = 0; n < 4; ++n) {
            int col = wc*64 + n*16 + l15;
            float bv = bias[col];
            #pragma unroll
            for (int r = 0; r < 4; ++r) {
                int row = row0 + wr*64 + m*16 + lk*4 + r;
                Cb[(size_t)row * 256 + col] = f2b(acc[m][n][r] + bv);
            }
        }
    }
}

// ------------------------------------------------- head GEMM (fp32 out, Nc=128)
__global__ __launch_bounds__(256) void gemm_bf16_head(
    const unsigned short* __restrict__ A, const unsigned short* __restrict__ Bt,
    const float* __restrict__ bias, float* __restrict__ C)
{
    __shared__ short ldsA[4][128][8];
    __shared__ short ldsB[4][128][8];
    const int tid  = threadIdx.x;
    const int wave = tid >> 6, lane = tid & 63;
    const int wr = wave >> 1, wc = wave & 1;
    const int l15 = lane & 15, lk = lane >> 4;
    const int row0 = blockIdx.x * 128;

    f32x4 acc[4][4] = {};
    for (int k0 = 0; k0 < 256; k0 += 32) {
        #pragma unroll
        for (int c = 0; c < 2; ++c) {
            int idx = c * 256 + tid;        // 0..511
            int ch = idx >> 7, r = idx & 127;
            GLOAD16(A  + (size_t)(row0 + r) * 256 + k0 + ch * 8, &ldsA[ch][r][0]);
            GLOAD16(Bt + (size_t)r * 256 + k0 + ch * 8, &ldsB[ch][r][0]);
        }
        __syncthreads();
        bf16x8 af[4], bf[4];
        #pragma unroll
        for (int m = 0; m < 4; ++m)
            af[m] = *reinterpret_cast<const bf16x8*>(&ldsA[lk][wr*64 + m*16 + l15][0]);
        #pragma unroll
        for (int n = 0; n < 4; ++n)
            bf[n] = *reinterpret_cast<const bf16x8*>(&ldsB[lk][wc*64 + n*16 + l15][0]);
        #pragma unroll
        for (int m = 0; m < 4; ++m)
            #pragma unroll
            for (int n = 0; n < 4; ++n)
                acc[m][n] = __builtin_amdgcn_mfma_f32_16x16x32_bf16(af[m], bf[n], acc[m][n], 0, 0, 0);
        __syncthreads();
    }
    #pragma unroll
    for (int m = 0; m < 4; ++m) {
        #pragma unroll
        for (int n = 0; n < 4; ++n) {
            int col = wc*64 + n*16 + l15;
            float bv = bias[col];
            #pragma unroll
            for (int r = 0; r < 4; ++r) {
                int row = row0 + wr*64 + m*16 + lk*4 + r;
                if (row < NN) C[(size_t)row * 128 + col] = acc[m][n][r] + bv;
            }
        }
    }
}

// --------------------------------------------------------------- cast kernels
__global__ __launch_bounds__(256) void cast_x_bf16(
    const float* __restrict__ x, unsigned short* __restrict__ xb)
{
    int idx = blockIdx.x * 256 + threadIdx.x;     // float4 index
    if (idx >= NM / 4) return;
    float4 v = reinterpret_cast<const float4*>(x)[idx];
    ushort4 o = { f2b(v.x), f2b(v.y), f2b(v.z), f2b(v.w) };
    *reinterpret_cast<ushort4*>(&xb[(size_t)idx * 4]) = o;
}

// W [K,Nc] fp32 -> Wt [Nc,K] bf16
__global__ __launch_bounds__(256) void cast_wt(
    const float* __restrict__ W, unsigned short* __restrict__ Wt, int K, int Nc)
{
    int i = blockIdx.x * 256 + threadIdx.x;
    if (i >= K * Nc) return;
    int k = i / Nc, n = i - k * Nc;
    Wt[n * K + k] = f2b(W[i]);
}

// ------------------------------------------------- per-node attention factors
// wave per node; writes el = exp(<H[n],a_l>), er = exp(<H[n],a_r>) per head
__global__ __launch_bounds__(256) void gat_scores_bf16(
    const unsigned short* __restrict__ Hb, const float* __restrict__ a_l,
    const float* __restrict__ a_r, float* __restrict__ el,
    float* __restrict__ er)
{
    const int wave = threadIdx.x >> 6;
    const int lane = threadIdx.x & 63;
    const int n = blockIdx.x * 4 + wave;
    if (n >= NN) return;
    const int c = lane * 4;
    const int h = lane >> 3;
    ushort4 hv = *reinterpret_cast<const ushort4*>(&Hb[(size_t)n * DIM + c]);
    float4 al4 = *reinterpret_cast<const float4*>(&a_l[c]);
    float4 ar4 = *reinterpret_cast<const float4*>(&a_r[c]);
    float x0 = b2f(hv.x), x1 = b2f(hv.y), x2 = b2f(hv.z), x3 = b2f(hv.w);
    float pl = x0*al4.x + x1*al4.y + x2*al4.z + x3*al4.w;
    float pr = x0*ar4.x + x1*ar4.y + x2*ar4.z + x3*ar4.w;
    #pragma unroll
    for (int o = 1; o < 8; o <<= 1) {
        pl += __shfl_xor(pl, o, 64);
        pr += __shfl_xor(pr, o, 64);
    }
    if ((lane & 7) == 0) {
        el[n * NH + h] = expf(pl);
        er[n * NH + h] = expf(pr);
    }
}

// edge decode: e2 in [0,NE): (ei0,ei1); [NE,2NE): reversed; [2NE,NE2): self
__device__ __forceinline__ void edge_sd(const int* __restrict__ ei, int e2,
                                        int& s, int& d)
{
    if (e2 < NE)          { s = ei[e2];      d = ei[e2 + NE]; }
    else if (e2 < 2 * NE) { s = ei[e2];      d = ei[e2 - NE]; }
    else                  { s = e2 - 2 * NE; d = s; }
}

// --------------------------------------------------------------- CSR build
__global__ __launch_bounds__(256) void deg_count(const int* __restrict__ ei,
                                                 int* __restrict__ deg)
{
    int e2 = blockIdx.x * 256 + threadIdx.x;
    if (e2 >= NE2) return;
    int s, d;
    edge_sd(ei, e2, s, d);
    atomicAdd(&deg[d], 1);
}

__global__ __launch_bounds__(256) void scan_block_sums(
    const int* __restrict__ deg, int* __restrict__ bsum)
{
    __shared__ int tmp[256];
    const int t = threadIdx.x;
    int i = blockIdx.x * 256 + t;
    tmp[t] = (i < NN) ? deg[i] : 0;
    __syncthreads();
    #pragma unroll
    for (int o = 128; o > 0; o >>= 1) {
        if (t < o) tmp[t] += tmp[t + o];
        __syncthreads();
    }
    if (t == 0) bsum[blockIdx.x] = tmp[0];
}

__global__ void scan_bsum(int* __restrict__ bsum)   // 1 block, 256 threads
{
    __shared__ int tmp[256];
    const int t = threadIdx.x;
    int v = (t < NBLK) ? bsum[t] : 0;
    tmp[t] = v;
    __syncthreads();
    #pragma unroll
    for (int o = 1; o < 256; o <<= 1) {
        int x = (t >= o) ? tmp[t - o] : 0;
        __syncthreads();
        tmp[t] += x;
        __syncthreads();
    }
    bsum[t] = tmp[t] - v;   // exclusive prefix of block sums
}

__global__ __launch_bounds__(256) void scan_write(
    const int* __restrict__ deg, const int* __restrict__ bsum,
    int* __restrict__ rowoff)
{
    __shared__ int tmp[256];
    const int t = threadIdx.x;
    int i = blockIdx.x * 256 + t;
    int v = (i < NN) ? deg[i] : 0;
    tmp[t] = v;
    __syncthreads();
    #pragma unroll
    for (int o = 1; o < 256; o <<= 1) {
        int x = (t >= o) ? tmp[t - o] : 0;
        __syncthreads();
        tmp[t] += x;
        __syncthreads();
    }
    if (i <= NN) rowoff[i] = bsum[blockIdx.x] + tmp[t] - v;
}

__global__ __launch_bounds__(256) void csr_fill(
    const int* __restrict__ ei, const int* __restrict__ rowoff,
    int* __restrict__ cursor, int* __restrict__ csr)
{
    int e2 = blockIdx.x * 256 + threadIdx.x;
    if (e2 >= NE2) return;
    int s, d;
    edge_sd(ei, e2, s, d);
    int pos = atomicAdd(&cursor[d], 1);
    csr[rowoff[d] + pos] = s;
}

// ------------------------- fused softmax + aggregation, no atomics, no expf
// out[d] = er[d]*sum(el[s]*H[s]) / (er[d]*sum(el[s]) + eps)
// Edge loop unrolled x8: 8 independent row-gathers in flight per wave (MLP).
__global__ __launch_bounds__(256) void gat_aggregate_csr_bf16(
    const int* __restrict__ csr, const int* __restrict__ rowoff,
    const unsigned short* __restrict__ Hb, const float* __restrict__ el,
    const float* __restrict__ er, unsigned short* __restrict__ outb)
{
    const int wid  = (blockIdx.x * 256 + threadIdx.x) >> 6;   // node id
    const int lane = threadIdx.x & 63;
    if (wid >= NN) return;
    const int h = lane >> 3;
    const int i0 = rowoff[wid], i1 = rowoff[wid + 1];
    const int c4 = lane * 4;

    float ax0 = 0.f, ay0 = 0.f, az0 = 0.f, aw0 = 0.f, den0 = 0.f;
    float ax1 = 0.f, ay1 = 0.f, az1 = 0.f, aw1 = 0.f, den1 = 0.f;

    int i = i0;
    for (; i + 8 <= i1; i += 8) {
        int s[8]; float e[8]; ushort4 hv[8];
        #pragma unroll
        for (int j = 0; j < 8; ++j) s[j] = csr[i + j];
        #pragma unroll
        for (int j = 0; j < 8; ++j) e[j] = el[s[j] * NH + h];
        #pragma unroll
        for (int j = 0; j < 8; ++j)
            hv[j] = *reinterpret_cast<const ushort4*>(&Hb[(size_t)s[j] * DIM + c4]);
        #pragma unroll
        for (int j = 0; j < 8; j += 2) {
            ax0 = fmaf(b2f(hv[j].x), e[j], ax0); ay0 = fmaf(b2f(hv[j].y), e[j], ay0);
            az0 = fmaf(b2f(hv[j].z), e[j], az0); aw0 = fmaf(b2f(hv[j].w), e[j], aw0);
            den0 += e[j];
            ax1 = fmaf(b2f(hv[j+1].x), e[j+1], ax1); ay1 = fmaf(b2f(hv[j+1].y), e[j+1], ay1);
            az1 = fmaf(b2f(hv[j+1].z), e[j+1], az1); aw1 = fmaf(b2f(hv[j+1].w), e[j+1], aw1);
            den1 += e[j+1];
        }
    }
    for (; i + 2 <= i1; i += 2) {
        int s0 = csr[i], s1 = csr[i + 1];
        float e0 = el[s0 * NH + h], e1 = el[s1 * NH + h];
        ushort4 h0 = *reinterpret_cast<const ushort4*>(&Hb[(size_t)s0 * DIM + c4]);
        ushort4 h1 = *reinterpret_cast<const ushort4*>(&Hb[(size_t)s1 * DIM + c4]);
        ax0 = fmaf(b2f(h0.x), e0, ax0); ay0 = fmaf(b2f(h0.y), e0, ay0);
        az0 = fmaf(b2f(h0.z), e0, az0); aw0 = fmaf(b2f(h0.w), e0, aw0);
        den0 += e0;
        ax1 = fmaf(b2f(h1.x), e1, ax1); ay1 = fmaf(b2f(h1.y), e1, ay1);
        az1 = fmaf(b2f(h1.z), e1, az1); aw1 = fmaf(b2f(h1.w), e1, aw1);
        den1 += e1;
    }
    if (i < i1) {
        int s = csr[i];
        float e = el[s * NH + h];
        ushort4 hv = *reinterpret_cast<const ushort4*>(&Hb[(size_t)s * DIM + c4]);
        ax0 = fmaf(b2f(hv.x), e, ax0); ay0 = fmaf(b2f(hv.y), e, ay0);
        az0 = fmaf(b2f(hv.z), e, az0); aw0 = fmaf(b2f(hv.w), e, aw0);
        den0 += e;
    }
    float ax = ax0 + ax1, ay = ay0 + ay1, az = az0 + az1, aw = aw0 + aw1;
    float den = den0 + den1;
    float erv = er[wid * NH + h];
    float inv = erv / fmaf(den, erv, 1e-12f);
    ushort4 r = { f2b(ax * inv), f2b(ay * inv), f2b(az * inv), f2b(aw * inv) };
    *reinterpret_cast<ushort4*>(&outb[(size_t)wid * DIM + c4]) = r;
}

// ------------------------------------------------------- BatchNorm (train)
__global__ __launch_bounds__(256) void bn_partial_bf16(
    const unsigned short* __restrict__ H, float* __restrict__ sums)
{
    const int c = threadIdx.x;
    const int r0 = blockIdx.x * 256;
    const int r1 = min(r0 + 256, NN);
    float s = 0.f, q = 0.f;
    for (int r = r0; r < r1; ++r) {
        float v = b2f(H[(size_t)r * DIM + c]);
        s += v;
        q = fmaf(v, v, q);
    }
    atomicAdd(&sums[c], s);
    atomicAdd(&sums[DIM + c], q);
}

// BN finalize (per-block, from sums) + affine + ReLU + bf16 out
__global__ __launch_bounds__(256) void bn_apply_relu_bf16(
    const unsigned short* __restrict__ in, const float* __restrict__ sums,
    const float* __restrict__ g, const float* __restrict__ be,
    unsigned short* __restrict__ out)
{
    __shared__ float sc[DIM], sh[DIM];
    const int t = threadIdx.x;
    {
        float mean = sums[t] * (1.f / NN);
        float var  = sums[DIM + t] * (1.f / NN) - mean * mean;
        float s    = g[t] * rsqrtf(var + 1e-5f);
        sc[t] = s;
        sh[t] = be[t] - mean * s;
    }
    __syncthreads();
    int idx = blockIdx.x * 256 + t;     // ushort4 index
    if (idx >= NM / 4) return;
    int c4 = (idx & 63) * 4;
    ushort4 v = reinterpret_cast<const ushort4*>(in)[idx];
    ushort4 r = {
        f2b(fmaxf(0.f, fmaf(b2f(v.x), sc[c4 + 0], sh[c4 + 0]))),
        f2b(fmaxf(0.f, fmaf(b2f(v.y), sc[c4 + 1], sh[c4 + 1]))),
        f2b(fmaxf(0.f, fmaf(b2f(v.z), sc[c4 + 2], sh[c4 + 2]))),
        f2b(fmaxf(0.f, fmaf(b2f(v.w), sc[c4 + 3], sh[c4 + 3]))) };
    reinterpret_cast<ushort4*>(out)[idx] = r;
}

// ---------------------------------------------------------------------------
extern "C" void kernel_launch(void* const* d_in, const int* in_sizes, int n_in,
                              void* d_out, int out_size, void* d_ws, size_t ws_size,
                              hipStream_t stream)
{
    const float* x   = (const float*)d_in[0];
    const int*   ei  = (const int*)  d_in[1];
    const float* W1  = (const float*)d_in[2];
    const float* b1  = (const float*)d_in[3];
    const float* al1 = (const float*)d_in[4];
    const float* ar1 = (const float*)d_in[5];
    const float* g1  = (const float*)d_in[6];
    const float* be1 = (const float*)d_in[7];
    const float* W2  = (const float*)d_in[8];
    const float* b2  = (const float*)d_in[9];
    const float* al2 = (const float*)d_in[10];
    const float* ar2 = (const float*)d_in[11];
    const float* g2  = (const float*)d_in[12];
    const float* be2 = (const float*)d_in[13];
    const float* Wh  = (const float*)d_in[14];
    const float* bh  = (const float*)d_in[15];
    float* out = (float*)d_out;

    float* ws     = (float*)d_ws;
    float* el     = ws;                      // NN*NH
    float* er     = el + NN * NH;            // NN*NH
    float* bnsum1 = er + NN * NH;            // 2*DIM
    float* bnsum2 = bnsum1 + 2 * DIM;        // 2*DIM  (adjacent: one memset)
    int*   deg    = (int*)(bnsum2 + 2 * DIM);// NN
    int*   cursor = deg + NN;                // NN     (adjacent: one memset)
    int*   rowoff = cursor + NN;             // NN+1
    int*   bsum   = rowoff + NN + 1;         // 256
    int*   csr    = bsum + 256;              // NE2
    unsigned short* xb =
        (unsigned short*)((((uintptr_t)(csr + NE2)) + 63) & ~(uintptr_t)63);
    unsigned short* Hb  = xb  + (size_t)MPAD * 256;  // MPAD*256
    unsigned short* Ab  = Hb  + (size_t)MPAD * 256;  // NN*256
    unsigned short* Wt1 = Ab  + (size_t)NN * 256;    // 256*256
    unsigned short* Wt2 = Wt1 + 256 * 256;
    unsigned short* Wth = Wt2 + 256 * 256;           // 128*256

    const int gemmBlocks  = MPAD / 128;              // 391
    const int edgeBlocks  = (NE2 + 255) / 256;       // 3321
    const int nodeBlocks  = (NN * 64 + 255) / 256;   // 12500 (wave per node)
    const int bnpBlocks   = (NN + 255) / 256;        // 196
    const int elemBlocks  = NM / 4 / 256;            // 12500

    // ---------------- weight / input casts
    cast_wt<<<(256 * 256 + 255) / 256, 256, 0, stream>>>(W1, Wt1, 256, 256);
    cast_wt<<<(256 * 256 + 255) / 256, 256, 0, stream>>>(W2, Wt2, 256, 256);
    cast_wt<<<(256 * 128 + 255) / 256, 256, 0, stream>>>(Wh, Wth, 256, 128);
    cast_x_bf16<<<elemBlocks, 256, 0, stream>>>(x, xb);

    // ---------------- zero scratch (deg+cursor adjacent; bnsum1+bnsum2 adjacent)
    hipMemsetAsync(deg, 0, 2 * NN * sizeof(int), stream);
    hipMemsetAsync(bnsum1, 0, 4 * DIM * sizeof(float), stream);

    // ---------------- CSR build (same graph both layers)
    deg_count<<<edgeBlocks, 256, 0, stream>>>(ei, deg);
    scan_block_sums<<<NBLK, 256, 0, stream>>>(deg, bsum);
    scan_bsum<<<1, 256, 0, stream>>>(bsum);
    scan_write<<<NBLK, 256, 0, stream>>>(deg, bsum, rowoff);
    csr_fill<<<edgeBlocks, 256, 0, stream>>>(ei, rowoff, cursor, csr);

    // ---------------- layer 1
    gemm_bf16_wide<<<gemmBlocks, 512, 0, stream>>>(xb, Wt1, b1, Hb);
    gat_scores_bf16<<<nodeBlocks, 256, 0, stream>>>(Hb, al1, ar1, el, er);
    gat_aggregate_csr_bf16<<<nodeBlocks, 256, 0, stream>>>(csr, rowoff, Hb, el, er, Ab);
    bn_partial_bf16<<<bnpBlocks, 256, 0, stream>>>(Ab, bnsum1);
    bn_apply_relu_bf16<<<elemBlocks, 256, 0, stream>>>(Ab, bnsum1, g1, be1, xb);

    // ---------------- layer 2
    gemm_bf16_wide<<<gemmBlocks, 512, 0, stream>>>(xb, Wt2, b2, Hb);
    gat_scores_bf16<<<nodeBlocks, 256, 0, stream>>>(Hb, al2, ar2, el, er);
    gat_aggregate_csr_bf16<<<nodeBlocks, 256, 0, stream>>>(csr, rowoff, Hb, el, er, Ab);
    bn_partial_bf16<<<bnpBlocks, 256, 0, stream>>>(Ab, bnsum2);
    bn_apply_relu_bf16<<<elemBlocks, 256, 0, stream>>>(Ab, bnsum2, g2, be2, xb);

    // ---------------- classification head
    gemm_bf16_head<<<gemmBlocks, 256, 0, stream>>>(xb, Wth, bh, out);
}